// Round 10
// baseline (844.983 us; speedup 1.0000x reference)
//
#include <hip/hip_runtime.h>

#define NN  100000
#define NNP 100096   // NN padded to multiple of 128
#define NE  1600000
#define DD  128

typedef __attribute__((ext_vector_type(8))) short bf16x8;
typedef __attribute__((ext_vector_type(4))) float f32x4;

__device__ __forceinline__ float bf2f(unsigned short u){
  union { unsigned int i; float f; } v; v.i = ((unsigned int)u) << 16; return v.f;
}
__device__ __forceinline__ unsigned short f2bf(float f){
  union { float f; unsigned int i; } v; v.f = f;
  unsigned int u = v.i;
  return (unsigned short)((u + 0x7fffu + ((u >> 16) & 1u)) >> 16);
}
__device__ __forceinline__ unsigned int cvt_pk_bf16(float lo, float hi){
  unsigned int r;
  asm("v_cvt_pk_bf16_f32 %0, %1, %2" : "=v"(r) : "v"(lo), "v"(hi));
  return r;
}

// ---------- all 8 weight matrices f32 -> bf16 in one launch ----------
struct WPtrs { const float* w[8]; };
__global__ __launch_bounds__(256) void cvt_w_all(WPtrs wp, unsigned short* __restrict__ o){
  int t = blockIdx.x * 256 + threadIdx.x;     // 65536 threads
  int m = t >> 13, i = t & 8191;
  float2 v = ((const float2*)wp.w[m])[i];
  ((unsigned int*)o)[t] = cvt_pk_bf16(v.x, v.y);
}

// ---------- stage one 128x128 bf16 matrix into LDS, k-chunk-major ----------
__device__ __forceinline__ void stage_mat(const unsigned short* __restrict__ Bg,
                                          unsigned short* sB){
  int t = threadIdx.x; // 256
  #pragma unroll
  for (int it = 0; it < 8; ++it){
    int idx = it * 256 + t;               // kc*128 + col
    int kc = idx >> 7, col = idx & 127;
    uint4 v = *(const uint4*)(Bg + (size_t)col * DD + kc * 8);
    *(uint4*)(sB + (size_t)idx * 8) = v;
  }
}

// ---------- edge GEMM chunk: stage W once, loop `cnt` 128-row tiles ----------
__device__ __forceinline__ void edge_run(const float* __restrict__ A,
    const unsigned short* __restrict__ Wg, const float* __restrict__ bias,
    float* __restrict__ out, unsigned short* sB, int tile0, int cnt)
{
  stage_mat(Wg, sB);
  __syncthreads();
  int wave = threadIdx.x >> 6, lane = threadIdx.x & 63;
  int lr = lane & 15, lk = lane >> 4;
  float bv[8];
  #pragma unroll
  for (int j = 0; j < 8; ++j) bv[j] = bias[j * 16 + lr];

  for (int t = 0; t < cnt; ++t){
    size_t r0 = (size_t)(tile0 + t) * 128 + (size_t)wave * 32;
    const float* Ap = A + (r0 + lr) * DD + lk * 8;
    bf16x8 a[2][4];
    #pragma unroll
    for (int g = 0; g < 2; ++g){
      #pragma unroll
      for (int ks = 0; ks < 4; ++ks){
        f32x4 a0 = *(const f32x4*)(Ap + (size_t)g * 16 * DD + ks * 32);
        f32x4 a1 = *(const f32x4*)(Ap + (size_t)g * 16 * DD + ks * 32 + 4);
        union { bf16x8 v; unsigned int u[4]; } au;
        au.u[0] = cvt_pk_bf16(a0[0], a0[1]);
        au.u[1] = cvt_pk_bf16(a0[2], a0[3]);
        au.u[2] = cvt_pk_bf16(a1[0], a1[1]);
        au.u[3] = cvt_pk_bf16(a1[2], a1[3]);
        a[g][ks] = au.v;
      }
    }
    f32x4 acc[2][8];
    #pragma unroll
    for (int g = 0; g < 2; ++g)
      #pragma unroll
      for (int j = 0; j < 8; ++j) acc[g][j] = (f32x4){0.f, 0.f, 0.f, 0.f};
    #pragma unroll
    for (int ks = 0; ks < 4; ++ks){
      #pragma unroll
      for (int j = 0; j < 8; ++j){
        bf16x8 b = *(const bf16x8*)(sB + ((ks * 4 + lk) * 128 + j * 16 + lr) * 8);
        acc[0][j] = __builtin_amdgcn_mfma_f32_16x16x32_bf16(a[0][ks], b, acc[0][j], 0, 0, 0);
        acc[1][j] = __builtin_amdgcn_mfma_f32_16x16x32_bf16(a[1][ks], b, acc[1][j], 0, 0, 0);
      }
    }
    #pragma unroll
    for (int g = 0; g < 2; ++g)
      #pragma unroll
      for (int j = 0; j < 8; ++j)
        #pragma unroll
        for (int r = 0; r < 4; ++r){
          size_t row = r0 + g * 16 + lk * 4 + r;
          out[row * DD + j * 16 + lr] = fmaxf(acc[g][j][r] + bv[j], 0.f);
        }
  }
}

#define EDGE_ARGS const float* __restrict__ eA, const unsigned short* __restrict__ eW, \
                  const float* __restrict__ eBias, float* __restrict__ eOut, \
                  int eTileBase, int eBlocks
#define EDGE_PASS eA, eW, eBias, eOut
#define EDGE_CHUNK 5

// ---------- CSR build (+ edge prefix blocks) ----------
__global__ __launch_bounds__(256) void countdeg_edge(
    const int* __restrict__ dst, int* __restrict__ deg, int n, EDGE_ARGS){
  __shared__ unsigned short sB[16384];
  if ((int)blockIdx.x < eBlocks){
    edge_run(EDGE_PASS, sB, eTileBase + blockIdx.x * EDGE_CHUNK, EDGE_CHUNK);
    return;
  }
  int t = (blockIdx.x - eBlocks) * 256 + threadIdx.x;
  if (t < n) atomicAdd(&deg[dst[t]], 1);
}

__global__ __launch_bounds__(256) void fillcsr_edge(
    const int* __restrict__ src, const int* __restrict__ dst,
    const int* __restrict__ row_start, int* __restrict__ cursor,
    int* __restrict__ csr, int n, EDGE_ARGS){
  __shared__ unsigned short sB[16384];
  if ((int)blockIdx.x < eBlocks){
    edge_run(EDGE_PASS, sB, eTileBase + blockIdx.x * EDGE_CHUNK, EDGE_CHUNK);
    return;
  }
  int t = (blockIdx.x - eBlocks) * 256 + threadIdx.x;
  if (t < n){
    int d = dst[t];
    int pos = atomicAdd(&cursor[d], 1);
    csr[row_start[d] + pos] = src[t];
  }
}

#define SCAN_CHUNK 1024
// ---------- partial sums (+ edge prefix) ----------
__global__ __launch_bounds__(256) void partials_edge(
    const int* __restrict__ deg, int* __restrict__ partials, int n, EDGE_ARGS){
  __shared__ unsigned short sB[16384];
  if ((int)blockIdx.x < eBlocks){
    edge_run(EDGE_PASS, sB, eTileBase + blockIdx.x * EDGE_CHUNK, EDGE_CHUNK);
    return;
  }
  int* lds = (int*)sB;               // host path aliases the edge buffer
  int hb = blockIdx.x - eBlocks;
  int t = threadIdx.x;
  int base = hb * SCAN_CHUNK + t * 4;
  int s = 0;
  #pragma unroll
  for (int i = 0; i < 4; ++i){ int idx = base + i; s += (idx < n) ? deg[idx] : 0; }
  lds[t] = s; __syncthreads();
  for (int off = 128; off > 0; off >>= 1){
    if (t < off) lds[t] += lds[t + off];
    __syncthreads();
  }
  if (t == 0) partials[hb] = lds[0];
}

// ---------- scan of partials: single-wave shfl scan (+ edge prefix) ----------
__global__ __launch_bounds__(256) void scanp_edge(int* partials, int nb, EDGE_ARGS){
  __shared__ unsigned short sB[16384];
  if ((int)blockIdx.x >= 1){
    int e = blockIdx.x - 1;
    if (e < eBlocks) edge_run(EDGE_PASS, sB, eTileBase + e * EDGE_CHUNK, EDGE_CHUNK);
    return;
  }
  if (threadIdx.x >= 64) return;     // one wave does the scan (nb <= 128)
  int lane = threadIdx.x;
  int o0 = (lane < nb) ? partials[lane] : 0;
  int o1 = (lane + 64 < nb) ? partials[lane + 64] : 0;
  int v0 = o0, v1 = o1;
  #pragma unroll
  for (int off = 1; off < 64; off <<= 1){
    int t = __shfl_up(v0, off, 64);
    if (lane >= off) v0 += t;
  }
  int tot0 = __shfl(v0, 63, 64);
  #pragma unroll
  for (int off = 1; off < 64; off <<= 1){
    int t = __shfl_up(v1, off, 64);
    if (lane >= off) v1 += t;
  }
  if (lane < nb)      partials[lane]      = v0 - o0;
  if (lane + 64 < nb) partials[lane + 64] = tot0 + v1 - o1;
}

// ---------- block scan (+ edge prefix) ----------
__global__ __launch_bounds__(256) void scanb_edge(
    const int* __restrict__ deg, const int* __restrict__ partials,
    int* __restrict__ row_start, int n, EDGE_ARGS){
  __shared__ unsigned short sB[16384];
  if ((int)blockIdx.x < eBlocks){
    edge_run(EDGE_PASS, sB, eTileBase + blockIdx.x * EDGE_CHUNK, EDGE_CHUNK);
    return;
  }
  int* lds = (int*)sB;
  int hb = blockIdx.x - eBlocks;
  int t = threadIdx.x;
  int base = hb * SCAN_CHUNK + t * 4;
  int v[4]; int s = 0;
  #pragma unroll
  for (int i = 0; i < 4; ++i){ int idx = base + i; v[i] = (idx < n) ? deg[idx] : 0; s += v[i]; }
  lds[t] = s; __syncthreads();
  for (int off = 1; off < 256; off <<= 1){
    int x = (t >= off) ? lds[t - off] : 0;
    __syncthreads();
    lds[t] += x;
    __syncthreads();
  }
  int excl = ((t == 0) ? 0 : lds[t - 1]) + partials[hb];
  #pragma unroll
  for (int i = 0; i < 4; ++i){ int idx = base + i; if (idx < n) row_start[idx] = excl; excl += v[i]; }
}

// ---------- h0 = bf16(item_emb[x]) ----------
__global__ __launch_bounds__(256) void gather_h0(const int* __restrict__ x,
                                                 const float* __restrict__ emb,
                                                 unsigned short* __restrict__ h, int n){
  int t = blockIdx.x * 256 + threadIdx.x;
  if (t >= n * 64) return;
  int node = t >> 6, p = t & 63;
  int s = x[node];
  float2 v = *(const float2*)(emb + (size_t)s * DD + p * 2);
  ((unsigned int*)h)[t] = cvt_pk_bf16(v.x, v.y);
}

__device__ __forceinline__ void add4(float* a, uint2 v){
  a[0] += bf2f((unsigned short)(v.x & 0xffffu)); a[1] += bf2f((unsigned short)(v.x >> 16));
  a[2] += bf2f((unsigned short)(v.y & 0xffffu)); a[3] += bf2f((unsigned short)(v.y >> 16));
}

// ---------- aggregate: uint2/lane, 2 neighbors per VMEM instr, 16 in flight ----------
// wave = 1 node; parity g=lane>>5 owns neighbors i+2k+g; lane covers cols (lane&31)*4..+4
__global__ __launch_bounds__(256) void aggregate4(const unsigned short* __restrict__ h,
                                                  const int* __restrict__ csr,
                                                  const int* __restrict__ row_start,
                                                  const int* __restrict__ deg,
                                                  unsigned short* __restrict__ mean, int n){
  int node = blockIdx.x * 4 + (threadIdx.x >> 6);   // grid*4 == NN exactly
  int lane = threadIdx.x & 63;
  int g = lane >> 5, c = lane & 31;
  int st = __builtin_amdgcn_readfirstlane(row_start[node]);
  int d  = __builtin_amdgcn_readfirstlane(deg[node]);
  const uint2* hp2 = (const uint2*)h;               // one row = 32 uint2
  float acc[4] = {0.f, 0.f, 0.f, 0.f};

  int i = 0;
  for (; i + 16 <= d; i += 16){
    int s[8];
    #pragma unroll
    for (int k = 0; k < 8; ++k) s[k] = csr[st + i + 2 * k + g];
    uint2 v[8];
    #pragma unroll
    for (int k = 0; k < 8; ++k) v[k] = hp2[(size_t)s[k] * 32 + c];
    #pragma unroll
    for (int k = 0; k < 8; ++k) add4(acc, v[k]);
  }
  for (; i + 4 <= d; i += 4){
    int s0 = csr[st + i + g], s1 = csr[st + i + 2 + g];
    uint2 v0 = hp2[(size_t)s0 * 32 + c];
    uint2 v1 = hp2[(size_t)s1 * 32 + c];
    add4(acc, v0); add4(acc, v1);
  }
  for (; i < d; i += 2){
    int ii = i + g;
    int s0 = csr[st + min(ii, d - 1)];
    uint2 v0 = hp2[(size_t)s0 * 32 + c];
    if (ii < d) add4(acc, v0);
  }
  #pragma unroll
  for (int j = 0; j < 4; ++j) acc[j] += __shfl_xor(acc[j], 32, 64);
  if (g == 0){
    float inv = 1.0f / fmaxf((float)d, 1.0f);
    uint2 o;
    o.x = cvt_pk_bf16(acc[0] * inv, acc[1] * inv);
    o.y = cvt_pk_bf16(acc[2] * inv, acc[3] * inv);
    ((uint2*)mean)[(size_t)node * 32 + c] = o;
  }
}

// ---------- node GEMM: sequential 32KB staging (+ edge prefix blocks) ----------
template<int DUAL, int OUTF32>
__global__ __launch_bounds__(256) void node_edge(
    const unsigned short* __restrict__ A1, const unsigned short* __restrict__ B1g,
    const unsigned short* __restrict__ A2, const unsigned short* __restrict__ B2g,
    const float* __restrict__ bias, void* __restrict__ outp, int M,
    EDGE_ARGS)
{
  __shared__ unsigned short sB[16384];   // 32KB, shared by edge path and staging
  if ((int)blockIdx.x < eBlocks){
    edge_run(EDGE_PASS, sB, eTileBase + blockIdx.x * EDGE_CHUNK, EDGE_CHUNK);
    return;
  }
  stage_mat(B1g, sB);
  int wave = threadIdx.x >> 6, lane = threadIdx.x & 63;
  int lr = lane & 15, lk = lane >> 4;
  float bv[8];
  #pragma unroll
  for (int j = 0; j < 8; ++j) bv[j] = bias[j * 16 + lr];

  int tile = blockIdx.x - eBlocks;
  size_t r0 = (size_t)tile * 128 + wave * 32;
  f32x4 acc[2][8];
  #pragma unroll
  for (int g = 0; g < 2; ++g)
    #pragma unroll
    for (int j = 0; j < 8; ++j) acc[g][j] = (f32x4){0.f, 0.f, 0.f, 0.f};

  bf16x8 a[2][4];
  {
    const unsigned short* Ap = A1 + (r0 + lr) * DD + lk * 8;
    #pragma unroll
    for (int g = 0; g < 2; ++g)
      #pragma unroll
      for (int ks = 0; ks < 4; ++ks)
        a[g][ks] = *(const bf16x8*)(Ap + (size_t)g * 16 * DD + ks * 32);
  }
  __syncthreads();   // B1 staged; A1 landed
  #pragma unroll
  for (int ks = 0; ks < 4; ++ks){
    #pragma unroll
    for (int j = 0; j < 8; ++j){
      bf16x8 b = *(const bf16x8*)(sB + ((ks * 4 + lk) * 128 + j * 16 + lr) * 8);
      acc[0][j] = __builtin_amdgcn_mfma_f32_16x16x32_bf16(a[0][ks], b, acc[0][j], 0, 0, 0);
      acc[1][j] = __builtin_amdgcn_mfma_f32_16x16x32_bf16(a[1][ks], b, acc[1][j], 0, 0, 0);
    }
  }
  if (DUAL){
    __syncthreads();                 // all waves done reading B1
    stage_mat(B2g, sB);
    {
      const unsigned short* Ap = A2 + (r0 + lr) * DD + lk * 8;
      #pragma unroll
      for (int g = 0; g < 2; ++g)
        #pragma unroll
        for (int ks = 0; ks < 4; ++ks)
          a[g][ks] = *(const bf16x8*)(Ap + (size_t)g * 16 * DD + ks * 32);
    }
    __syncthreads();                 // B2 staged; A2 landed
    #pragma unroll
    for (int ks = 0; ks < 4; ++ks){
      #pragma unroll
      for (int j = 0; j < 8; ++j){
        bf16x8 b = *(const bf16x8*)(sB + ((ks * 4 + lk) * 128 + j * 16 + lr) * 8);
        acc[0][j] = __builtin_amdgcn_mfma_f32_16x16x32_bf16(a[0][ks], b, acc[0][j], 0, 0, 0);
        acc[1][j] = __builtin_amdgcn_mfma_f32_16x16x32_bf16(a[1][ks], b, acc[1][j], 0, 0, 0);
      }
    }
  }
  #pragma unroll
  for (int g = 0; g < 2; ++g)
    #pragma unroll
    for (int j = 0; j < 8; ++j)
      #pragma unroll
      for (int r = 0; r < 4; ++r){
        size_t row = r0 + g * 16 + lk * 4 + r;
        float v = fmaxf(acc[g][j][r] + bv[j], 0.f);
        if (OUTF32){
          if (row < (size_t)M) ((float*)outp)[row * DD + j * 16 + lr] = v;
        } else {
          ((unsigned short*)outp)[row * DD + j * 16 + lr] = f2bf(v);
        }
      }
}

extern "C" void kernel_launch(void* const* d_in, const int* in_sizes, int n_in,
                              void* d_out, int out_size, void* d_ws, size_t ws_size,
                              hipStream_t stream)
{
  const int*   x    = (const int*)d_in[0];
  const int*   ei   = (const int*)d_in[1];
  const int*   srcp = ei;
  const int*   dstp = ei + NE;
  const float* item = (const float*)d_in[3];
  const float* eemb = (const float*)d_in[4];
  WPtrs wp;
  wp.w[0] = (const float*)d_in[5];  // Wl1
  wp.w[1] = (const float*)d_in[7];  // Wr1
  wp.w[2] = (const float*)d_in[8];  // Wl2
  wp.w[3] = (const float*)d_in[10]; // Wr2
  wp.w[4] = (const float*)d_in[11]; // Wl3
  wp.w[5] = (const float*)d_in[13]; // Wr3
  wp.w[6] = (const float*)d_in[14]; // W_lin1
  wp.w[7] = (const float*)d_in[16]; // W_lin2
  const float* bl1 = (const float*)d_in[6];
  const float* bl2 = (const float*)d_in[9];
  const float* bl3 = (const float*)d_in[12];
  const float* bq1 = (const float*)d_in[15];
  const float* bq2 = (const float*)d_in[17];

  char* ws = (char*)d_ws;
  size_t o = 0;
  auto alloc = [&](size_t bytes) -> void* {
    void* p = ws + o;
    o += (bytes + 255) & ~(size_t)255;
    return p;
  };
  unsigned short* wbf      = (unsigned short*)alloc(8 * 16384 * 2);
  int*            deg      = (int*)alloc((size_t)NNP * 4);
  int*            cursor   = (int*)alloc((size_t)NNP * 4);
  int*            row_st   = (int*)alloc((size_t)NNP * 4);
  int*            partials = (int*)alloc(4096);
  int*            csr      = (int*)alloc((size_t)NE * 4);
  unsigned short* mean     = (unsigned short*)alloc((size_t)NNP * DD * 2);
  unsigned short* h_a      = (unsigned short*)alloc((size_t)NNP * DD * 2);
  unsigned short* h_b      = (unsigned short*)alloc((size_t)NNP * DD * 2);

  float* out_h = (float*)d_out;
  float* out_e = out_h + (size_t)NN * DD;
  const unsigned short* eW = wbf + 7 * 16384;

  // zero deg + cursor (adjacent 256-aligned allocations)
  hipMemsetAsync(deg, 0, (size_t)NNP * 4 * 2, stream);

  cvt_w_all<<<256, 256, 0, stream>>>(wp, wbf);

  // edge tile distribution: 12500 tiles, 5/block, 2500 edge blocks total
  // cd 250 + ps 100 + sp 100 + sb 100 + fc 250 + nd 450*3 + fin 350 = 2500
  int eb = 0;
  const int e_cd = 250, e_ps = 100, e_sp = 100, e_sb = 100, e_fc = 250;
  const int e_nd = 450, e_fin = 350;

  const int nb = (NN + SCAN_CHUNK - 1) / SCAN_CHUNK;      // 98
  const int csr_blk = (NE + 255) / 256;                   // 6250

  countdeg_edge<<<e_cd + csr_blk, 256, 0, stream>>>(dstp, deg, NE,
      eemb, eW, bq2, out_e, eb * EDGE_CHUNK, e_cd); eb += e_cd;
  partials_edge<<<e_ps + nb, 256, 0, stream>>>(deg, partials, NN,
      eemb, eW, bq2, out_e, eb * EDGE_CHUNK, e_ps); eb += e_ps;
  scanp_edge<<<1 + e_sp, 256, 0, stream>>>(partials, nb,
      eemb, eW, bq2, out_e, eb * EDGE_CHUNK, e_sp); eb += e_sp;
  scanb_edge<<<e_sb + nb, 256, 0, stream>>>(deg, partials, row_st, NN,
      eemb, eW, bq2, out_e, eb * EDGE_CHUNK, e_sb); eb += e_sb;
  fillcsr_edge<<<e_fc + csr_blk, 256, 0, stream>>>(srcp, dstp, row_st, cursor, csr, NE,
      eemb, eW, bq2, out_e, eb * EDGE_CHUNK, e_fc); eb += e_fc;

  gather_h0<<<(NN * 64 + 255) / 256, 256, 0, stream>>>(x, item, h_a, NN);

  const int agg_grid   = (NN + 3) / 4;      // 25000
  const int node_tiles = NNP / 128;         // 782

  // layer 1: h_a -> h_b
  aggregate4<<<agg_grid, 256, 0, stream>>>(h_a, csr, row_st, deg, mean, NN);
  node_edge<1,0><<<e_nd + node_tiles, 256, 0, stream>>>(mean, wbf + 0*16384, h_a, wbf + 1*16384,
      bl1, h_b, NN, eemb, eW, bq2, out_e, eb * EDGE_CHUNK, e_nd); eb += e_nd;
  // layer 2: h_b -> h_a
  aggregate4<<<agg_grid, 256, 0, stream>>>(h_b, csr, row_st, deg, mean, NN);
  node_edge<1,0><<<e_nd + node_tiles, 256, 0, stream>>>(mean, wbf + 2*16384, h_b, wbf + 3*16384,
      bl2, h_a, NN, eemb, eW, bq2, out_e, eb * EDGE_CHUNK, e_nd); eb += e_nd;
  // layer 3: h_a -> h_b
  aggregate4<<<agg_grid, 256, 0, stream>>>(h_a, csr, row_st, deg, mean, NN);
  node_edge<1,0><<<e_nd + node_tiles, 256, 0, stream>>>(mean, wbf + 4*16384, h_a, wbf + 5*16384,
      bl3, h_b, NN, eemb, eW, bq2, out_e, eb * EDGE_CHUNK, e_nd); eb += e_nd;

  // final node linear -> f32 out (+ last edge chunk)
  node_edge<0,1><<<e_fin + node_tiles, 256, 0, stream>>>(h_b, wbf + 6*16384, h_b, wbf + 6*16384,
      bq1, out_h, NN, eemb, eW, bq2, out_e, eb * EDGE_CHUNK, e_fin); eb += e_fin;
}

// Round 11
// 794.295 us; speedup vs baseline: 1.0638x; 1.0638x over previous
//
#include <hip/hip_runtime.h>

#define NN  100000
#define NNP 100096   // NN padded to multiple of 128
#define NE  1600000
#define DD  128

typedef __attribute__((ext_vector_type(8))) short bf16x8;
typedef __attribute__((ext_vector_type(4))) float f32x4;

__device__ __forceinline__ float bf2f(unsigned short u){
  union { unsigned int i; float f; } v; v.i = ((unsigned int)u) << 16; return v.f;
}
__device__ __forceinline__ unsigned short f2bf(float f){
  union { float f; unsigned int i; } v; v.f = f;
  unsigned int u = v.i;
  return (unsigned short)((u + 0x7fffu + ((u >> 16) & 1u)) >> 16);
}
__device__ __forceinline__ unsigned int cvt_pk_bf16(float lo, float hi){
  unsigned int r;
  asm("v_cvt_pk_bf16_f32 %0, %1, %2" : "=v"(r) : "v"(lo), "v"(hi));
  return r;
}

// ---------- all 8 weight matrices f32 -> bf16 in one launch ----------
struct WPtrs { const float* w[8]; };
__global__ __launch_bounds__(256) void cvt_w_all(WPtrs wp, unsigned short* __restrict__ o){
  int t = blockIdx.x * 256 + threadIdx.x;     // 65536 threads
  int m = t >> 13, i = t & 8191;
  float2 v = ((const float2*)wp.w[m])[i];
  ((unsigned int*)o)[t] = cvt_pk_bf16(v.x, v.y);
}

// ---------- stage one 128x128 bf16 matrix into LDS, k-chunk-major ----------
__device__ __forceinline__ void stage_mat(const unsigned short* __restrict__ Bg,
                                          unsigned short* sB){
  int t = threadIdx.x; // 256
  #pragma unroll
  for (int it = 0; it < 8; ++it){
    int idx = it * 256 + t;               // kc*128 + col
    int kc = idx >> 7, col = idx & 127;
    uint4 v = *(const uint4*)(Bg + (size_t)col * DD + kc * 8);
    *(uint4*)(sB + (size_t)idx * 8) = v;
  }
}

// ---------- edge GEMM chunk: stage W once, loop `cnt` 128-row tiles ----------
__device__ __forceinline__ void edge_run(const float* __restrict__ A,
    const unsigned short* __restrict__ Wg, const float* __restrict__ bias,
    float* __restrict__ out, unsigned short* sB, int tile0, int cnt)
{
  stage_mat(Wg, sB);
  __syncthreads();
  int wave = threadIdx.x >> 6, lane = threadIdx.x & 63;
  int lr = lane & 15, lk = lane >> 4;
  float bv[8];
  #pragma unroll
  for (int j = 0; j < 8; ++j) bv[j] = bias[j * 16 + lr];

  for (int t = 0; t < cnt; ++t){
    size_t r0 = (size_t)(tile0 + t) * 128 + (size_t)wave * 32;
    const float* Ap = A + (r0 + lr) * DD + lk * 8;
    bf16x8 a[2][4];
    #pragma unroll
    for (int g = 0; g < 2; ++g){
      #pragma unroll
      for (int ks = 0; ks < 4; ++ks){
        f32x4 a0 = *(const f32x4*)(Ap + (size_t)g * 16 * DD + ks * 32);
        f32x4 a1 = *(const f32x4*)(Ap + (size_t)g * 16 * DD + ks * 32 + 4);
        union { bf16x8 v; unsigned int u[4]; } au;
        au.u[0] = cvt_pk_bf16(a0[0], a0[1]);
        au.u[1] = cvt_pk_bf16(a0[2], a0[3]);
        au.u[2] = cvt_pk_bf16(a1[0], a1[1]);
        au.u[3] = cvt_pk_bf16(a1[2], a1[3]);
        a[g][ks] = au.v;
      }
    }
    f32x4 acc[2][8];
    #pragma unroll
    for (int g = 0; g < 2; ++g)
      #pragma unroll
      for (int j = 0; j < 8; ++j) acc[g][j] = (f32x4){0.f, 0.f, 0.f, 0.f};
    #pragma unroll
    for (int ks = 0; ks < 4; ++ks){
      #pragma unroll
      for (int j = 0; j < 8; ++j){
        bf16x8 b = *(const bf16x8*)(sB + ((ks * 4 + lk) * 128 + j * 16 + lr) * 8);
        acc[0][j] = __builtin_amdgcn_mfma_f32_16x16x32_bf16(a[0][ks], b, acc[0][j], 0, 0, 0);
        acc[1][j] = __builtin_amdgcn_mfma_f32_16x16x32_bf16(a[1][ks], b, acc[1][j], 0, 0, 0);
      }
    }
    #pragma unroll
    for (int g = 0; g < 2; ++g)
      #pragma unroll
      for (int j = 0; j < 8; ++j)
        #pragma unroll
        for (int r = 0; r < 4; ++r){
          size_t row = r0 + g * 16 + lk * 4 + r;
          out[row * DD + j * 16 + lr] = fmaxf(acc[g][j][r] + bv[j], 0.f);
        }
  }
}

#define EDGE_ARGS const float* __restrict__ eA, const unsigned short* __restrict__ eW, \
                  const float* __restrict__ eBias, float* __restrict__ eOut, \
                  int eTileBase, int eBlocks
#define EDGE_PASS eA, eW, eBias, eOut
#define EDGE_CHUNK 5

// ---------- CSR count (+ edge prefix blocks) ----------
__global__ __launch_bounds__(256) void countdeg_edge(
    const int* __restrict__ dst, int* __restrict__ deg, int n, EDGE_ARGS){
  __shared__ unsigned short sB[16384];
  if ((int)blockIdx.x < eBlocks){
    edge_run(EDGE_PASS, sB, eTileBase + blockIdx.x * EDGE_CHUNK, EDGE_CHUNK);
    return;
  }
  int t = (blockIdx.x - eBlocks) * 256 + threadIdx.x;
  if (t < n) atomicAdd(&deg[dst[t]], 1);
}

// ---------- CSR fill + h0 gather (+ edge prefix blocks), 3 block ranges ----------
__global__ __launch_bounds__(256) void fillcsr_h0_edge(
    const int* __restrict__ src, const int* __restrict__ dst,
    const int* __restrict__ row_start, int* __restrict__ cursor,
    int* __restrict__ csr, int n, int csrBlk,
    const int* __restrict__ x, const float* __restrict__ item,
    unsigned short* __restrict__ h0, int nh, EDGE_ARGS){
  __shared__ unsigned short sB[16384];
  if ((int)blockIdx.x < eBlocks){
    edge_run(EDGE_PASS, sB, eTileBase + blockIdx.x * EDGE_CHUNK, EDGE_CHUNK);
    return;
  }
  int hb = blockIdx.x - eBlocks;
  if (hb < csrBlk){
    int t = hb * 256 + threadIdx.x;
    if (t < n){
      int d = dst[t];
      int pos = atomicAdd(&cursor[d], 1);
      csr[row_start[d] + pos] = src[t];
    }
    return;
  }
  int t = (hb - csrBlk) * 256 + threadIdx.x;
  if (t < nh){
    int node = t >> 6, p = t & 63;
    int s = x[node];
    float2 v = *(const float2*)(item + (size_t)s * DD + p * 2);
    ((unsigned int*)h0)[t] = cvt_pk_bf16(v.x, v.y);
  }
}

#define SCAN_CHUNK 1024
__global__ __launch_bounds__(256) void partial_sums(const int* __restrict__ deg,
                                                    int* __restrict__ partials, int n){
  __shared__ int lds[256];
  int t = threadIdx.x;
  int base = blockIdx.x * SCAN_CHUNK + t * 4;
  int s = 0;
  #pragma unroll
  for (int i = 0; i < 4; ++i){ int idx = base + i; s += (idx < n) ? deg[idx] : 0; }
  lds[t] = s; __syncthreads();
  for (int off = 128; off > 0; off >>= 1){
    if (t < off) lds[t] += lds[t + off];
    __syncthreads();
  }
  if (t == 0) partials[blockIdx.x] = lds[0];
}

// ---------- scan of partials: single-wave shfl scan (nb <= 128) ----------
__global__ __launch_bounds__(64) void scanp_wave(int* partials, int nb){
  int lane = threadIdx.x;
  int o0 = (lane < nb) ? partials[lane] : 0;
  int o1 = (lane + 64 < nb) ? partials[lane + 64] : 0;
  int v0 = o0, v1 = o1;
  #pragma unroll
  for (int off = 1; off < 64; off <<= 1){
    int t = __shfl_up(v0, off, 64);
    if (lane >= off) v0 += t;
  }
  int tot0 = __shfl(v0, 63, 64);
  #pragma unroll
  for (int off = 1; off < 64; off <<= 1){
    int t = __shfl_up(v1, off, 64);
    if (lane >= off) v1 += t;
  }
  if (lane < nb)      partials[lane]      = v0 - o0;
  if (lane + 64 < nb) partials[lane + 64] = tot0 + v1 - o1;
}

__global__ __launch_bounds__(256) void scan_block(const int* __restrict__ deg,
                                                  const int* __restrict__ partials,
                                                  int* __restrict__ row_start, int n){
  __shared__ int lds[256];
  int t = threadIdx.x;
  int base = blockIdx.x * SCAN_CHUNK + t * 4;
  int v[4]; int s = 0;
  #pragma unroll
  for (int i = 0; i < 4; ++i){ int idx = base + i; v[i] = (idx < n) ? deg[idx] : 0; s += v[i]; }
  lds[t] = s; __syncthreads();
  for (int off = 1; off < 256; off <<= 1){
    int x = (t >= off) ? lds[t - off] : 0;
    __syncthreads();
    lds[t] += x;
    __syncthreads();
  }
  int excl = ((t == 0) ? 0 : lds[t - 1]) + partials[blockIdx.x];
  #pragma unroll
  for (int i = 0; i < 4; ++i){ int idx = base + i; if (idx < n) row_start[idx] = excl; excl += v[i]; }
}

// ---------- mean aggregation: 8 neighbors in flight + scalar idx loads ----------
__global__ __launch_bounds__(256) void aggregate3(const unsigned short* __restrict__ h,
                                                  const int* __restrict__ csr,
                                                  const int* __restrict__ row_start,
                                                  const int* __restrict__ deg,
                                                  unsigned short* __restrict__ mean, int n){
  int node = blockIdx.x * 4 + (threadIdx.x >> 6);
  int lane = threadIdx.x & 63;
  // wave-uniform -> force scalar so csr index reads go down the SMEM pipe
  int st = __builtin_amdgcn_readfirstlane(row_start[node]);
  int d  = __builtin_amdgcn_readfirstlane(deg[node]);
  const unsigned int* hp = (const unsigned int*)h;
  float a0[8], a1[8];
  #pragma unroll
  for (int k = 0; k < 8; ++k){ a0[k] = 0.f; a1[k] = 0.f; }
  int i = 0;
  for (; i + 8 <= d; i += 8){
    int idx[8];
    #pragma unroll
    for (int k = 0; k < 8; ++k) idx[k] = csr[st + i + k];
    unsigned int v[8];
    #pragma unroll
    for (int k = 0; k < 8; ++k) v[k] = hp[(size_t)idx[k] * 64 + lane];
    #pragma unroll
    for (int k = 0; k < 8; ++k){
      a0[k] += bf2f((unsigned short)(v[k] & 0xffffu));
      a1[k] += bf2f((unsigned short)(v[k] >> 16));
    }
  }
  for (; i + 4 <= d; i += 4){
    int idx[4];
    #pragma unroll
    for (int k = 0; k < 4; ++k) idx[k] = csr[st + i + k];
    unsigned int v[4];
    #pragma unroll
    for (int k = 0; k < 4; ++k) v[k] = hp[(size_t)idx[k] * 64 + lane];
    #pragma unroll
    for (int k = 0; k < 4; ++k){
      a0[k] += bf2f((unsigned short)(v[k] & 0xffffu));
      a1[k] += bf2f((unsigned short)(v[k] >> 16));
    }
  }
  for (; i < d; ++i){
    int s = csr[st + i];
    unsigned int v = hp[(size_t)s * 64 + lane];
    a0[0] += bf2f((unsigned short)(v & 0xffffu));
    a1[0] += bf2f((unsigned short)(v >> 16));
  }
  float s0 = ((a0[0] + a0[1]) + (a0[2] + a0[3])) + ((a0[4] + a0[5]) + (a0[6] + a0[7]));
  float s1 = ((a1[0] + a1[1]) + (a1[2] + a1[3])) + ((a1[4] + a1[5]) + (a1[6] + a1[7]));
  float inv = 1.0f / fmaxf((float)d, 1.0f);
  ((unsigned int*)mean)[(size_t)node * 64 + lane] = cvt_pk_bf16(s0 * inv, s1 * inv);
}

// ---------- node GEMM: sequential 32KB staging (+ edge prefix blocks) ----------
template<int DUAL, int OUTF32>
__global__ __launch_bounds__(256) void node_edge(
    const unsigned short* __restrict__ A1, const unsigned short* __restrict__ B1g,
    const unsigned short* __restrict__ A2, const unsigned short* __restrict__ B2g,
    const float* __restrict__ bias, void* __restrict__ outp, int M,
    EDGE_ARGS)
{
  __shared__ unsigned short sB[16384];   // 32KB, shared by edge path and staging
  if ((int)blockIdx.x < eBlocks){
    edge_run(EDGE_PASS, sB, eTileBase + blockIdx.x * EDGE_CHUNK, EDGE_CHUNK);
    return;
  }
  stage_mat(B1g, sB);
  int wave = threadIdx.x >> 6, lane = threadIdx.x & 63;
  int lr = lane & 15, lk = lane >> 4;
  float bv[8];
  #pragma unroll
  for (int j = 0; j < 8; ++j) bv[j] = bias[j * 16 + lr];

  int tile = blockIdx.x - eBlocks;
  size_t r0 = (size_t)tile * 128 + wave * 32;
  f32x4 acc[2][8];
  #pragma unroll
  for (int g = 0; g < 2; ++g)
    #pragma unroll
    for (int j = 0; j < 8; ++j) acc[g][j] = (f32x4){0.f, 0.f, 0.f, 0.f};

  bf16x8 a[2][4];
  {
    const unsigned short* Ap = A1 + (r0 + lr) * DD + lk * 8;
    #pragma unroll
    for (int g = 0; g < 2; ++g)
      #pragma unroll
      for (int ks = 0; ks < 4; ++ks)
        a[g][ks] = *(const bf16x8*)(Ap + (size_t)g * 16 * DD + ks * 32);
  }
  __syncthreads();   // B1 staged; A1 landed
  #pragma unroll
  for (int ks = 0; ks < 4; ++ks){
    #pragma unroll
    for (int j = 0; j < 8; ++j){
      bf16x8 b = *(const bf16x8*)(sB + ((ks * 4 + lk) * 128 + j * 16 + lr) * 8);
      acc[0][j] = __builtin_amdgcn_mfma_f32_16x16x32_bf16(a[0][ks], b, acc[0][j], 0, 0, 0);
      acc[1][j] = __builtin_amdgcn_mfma_f32_16x16x32_bf16(a[1][ks], b, acc[1][j], 0, 0, 0);
    }
  }
  if (DUAL){
    __syncthreads();                 // all waves done reading B1
    stage_mat(B2g, sB);
    {
      const unsigned short* Ap = A2 + (r0 + lr) * DD + lk * 8;
      #pragma unroll
      for (int g = 0; g < 2; ++g)
        #pragma unroll
        for (int ks = 0; ks < 4; ++ks)
          a[g][ks] = *(const bf16x8*)(Ap + (size_t)g * 16 * DD + ks * 32);
    }
    __syncthreads();                 // B2 staged; A2 landed
    #pragma unroll
    for (int ks = 0; ks < 4; ++ks){
      #pragma unroll
      for (int j = 0; j < 8; ++j){
        bf16x8 b = *(const bf16x8*)(sB + ((ks * 4 + lk) * 128 + j * 16 + lr) * 8);
        acc[0][j] = __builtin_amdgcn_mfma_f32_16x16x32_bf16(a[0][ks], b, acc[0][j], 0, 0, 0);
        acc[1][j] = __builtin_amdgcn_mfma_f32_16x16x32_bf16(a[1][ks], b, acc[1][j], 0, 0, 0);
      }
    }
  }
  #pragma unroll
  for (int g = 0; g < 2; ++g)
    #pragma unroll
    for (int j = 0; j < 8; ++j)
      #pragma unroll
      for (int r = 0; r < 4; ++r){
        size_t row = r0 + g * 16 + lk * 4 + r;
        float v = fmaxf(acc[g][j][r] + bv[j], 0.f);
        if (OUTF32){
          if (row < (size_t)M) ((float*)outp)[row * DD + j * 16 + lr] = v;
        } else {
          ((unsigned short*)outp)[row * DD + j * 16 + lr] = f2bf(v);
        }
      }
}

extern "C" void kernel_launch(void* const* d_in, const int* in_sizes, int n_in,
                              void* d_out, int out_size, void* d_ws, size_t ws_size,
                              hipStream_t stream)
{
  const int*   x    = (const int*)d_in[0];
  const int*   ei   = (const int*)d_in[1];
  const int*   srcp = ei;
  const int*   dstp = ei + NE;
  const float* item = (const float*)d_in[3];
  const float* eemb = (const float*)d_in[4];
  WPtrs wp;
  wp.w[0] = (const float*)d_in[5];  // Wl1
  wp.w[1] = (const float*)d_in[7];  // Wr1
  wp.w[2] = (const float*)d_in[8];  // Wl2
  wp.w[3] = (const float*)d_in[10]; // Wr2
  wp.w[4] = (const float*)d_in[11]; // Wl3
  wp.w[5] = (const float*)d_in[13]; // Wr3
  wp.w[6] = (const float*)d_in[14]; // W_lin1
  wp.w[7] = (const float*)d_in[16]; // W_lin2
  const float* bl1 = (const float*)d_in[6];
  const float* bl2 = (const float*)d_in[9];
  const float* bl3 = (const float*)d_in[12];
  const float* bq1 = (const float*)d_in[15];
  const float* bq2 = (const float*)d_in[17];

  char* ws = (char*)d_ws;
  size_t o = 0;
  auto alloc = [&](size_t bytes) -> void* {
    void* p = ws + o;
    o += (bytes + 255) & ~(size_t)255;
    return p;
  };
  unsigned short* wbf      = (unsigned short*)alloc(8 * 16384 * 2);
  int*            deg      = (int*)alloc((size_t)NNP * 4);
  int*            cursor   = (int*)alloc((size_t)NNP * 4);
  int*            row_st   = (int*)alloc((size_t)NNP * 4);
  int*            partials = (int*)alloc(4096);
  int*            csr      = (int*)alloc((size_t)NE * 4);
  unsigned short* mean     = (unsigned short*)alloc((size_t)NNP * DD * 2);
  unsigned short* h_a      = (unsigned short*)alloc((size_t)NNP * DD * 2);
  unsigned short* h_b      = (unsigned short*)alloc((size_t)NNP * DD * 2);

  float* out_h = (float*)d_out;
  float* out_e = out_h + (size_t)NN * DD;
  const unsigned short* eW = wbf + 7 * 16384;

  // zero deg + cursor (adjacent 256-aligned allocations)
  hipMemsetAsync(deg, 0, (size_t)NNP * 4 * 2, stream);

  cvt_w_all<<<256, 256, 0, stream>>>(wp, wbf);

  // edge tile distribution: 12500 tiles total, 5 per edge block (R9 layout)
  int eb = 0;
  const int e_cd = 250, e_fc = 250, e_nd = 500, e_fin = 500;

  const int nb = (NN + SCAN_CHUNK - 1) / SCAN_CHUNK;      // 98
  const int csr_blk = (NE + 255) / 256;                   // 6250
  const int h0_blk  = (NN * 64 + 255) / 256;              // 25000

  countdeg_edge<<<e_cd + csr_blk, 256, 0, stream>>>(dstp, deg, NE,
      eemb, eW, bq2, out_e, eb * EDGE_CHUNK, e_cd); eb += e_cd;
  partial_sums<<<nb, 256, 0, stream>>>(deg, partials, NN);
  scanp_wave<<<1, 64, 0, stream>>>(partials, nb);
  scan_block<<<nb, 256, 0, stream>>>(deg, partials, row_st, NN);
  fillcsr_h0_edge<<<e_fc + csr_blk + h0_blk, 256, 0, stream>>>(
      srcp, dstp, row_st, cursor, csr, NE, csr_blk,
      x, item, h_a, NN * 64,
      eemb, eW, bq2, out_e, eb * EDGE_CHUNK, e_fc); eb += e_fc;

  const int agg_grid   = (NN + 3) / 4;      // 25000
  const int node_tiles = NNP / 128;         // 782

  // layer 1: h_a -> h_b
  aggregate3<<<agg_grid, 256, 0, stream>>>(h_a, csr, row_st, deg, mean, NN);
  node_edge<1,0><<<e_nd + node_tiles, 256, 0, stream>>>(mean, wbf + 0*16384, h_a, wbf + 1*16384,
      bl1, h_b, NN, eemb, eW, bq2, out_e, eb * EDGE_CHUNK, e_nd); eb += e_nd;
  // layer 2: h_b -> h_a
  aggregate3<<<agg_grid, 256, 0, stream>>>(h_b, csr, row_st, deg, mean, NN);
  node_edge<1,0><<<e_nd + node_tiles, 256, 0, stream>>>(mean, wbf + 2*16384, h_b, wbf + 3*16384,
      bl2, h_a, NN, eemb, eW, bq2, out_e, eb * EDGE_CHUNK, e_nd); eb += e_nd;
  // layer 3: h_a -> h_b
  aggregate3<<<agg_grid, 256, 0, stream>>>(h_a, csr, row_st, deg, mean, NN);
  node_edge<1,0><<<e_nd + node_tiles, 256, 0, stream>>>(mean, wbf + 4*16384, h_a, wbf + 5*16384,
      bl3, h_b, NN, eemb, eW, bq2, out_e, eb * EDGE_CHUNK, e_nd); eb += e_nd;

  // final node linear -> f32 out (+ last edge chunk)
  node_edge<0,1><<<e_fin + node_tiles, 256, 0, stream>>>(h_b, wbf + 6*16384, h_b, wbf + 6*16384,
      bq1, out_h, NN, eemb, eW, bq2, out_e, eb * EDGE_CHUNK, e_fin); eb += e_fin;
}

// Round 12
// 793.266 us; speedup vs baseline: 1.0652x; 1.0013x over previous
//
#include <hip/hip_runtime.h>

#define NN  100000
#define NNP 100096   // NN padded to multiple of 128
#define NE  1600000
#define DD  128

typedef __attribute__((ext_vector_type(8))) short bf16x8;
typedef __attribute__((ext_vector_type(4))) float f32x4;

__device__ __forceinline__ float bf2f(unsigned short u){
  union { unsigned int i; float f; } v; v.i = ((unsigned int)u) << 16; return v.f;
}
__device__ __forceinline__ unsigned short f2bf(float f){
  union { float f; unsigned int i; } v; v.f = f;
  unsigned int u = v.i;
  return (unsigned short)((u + 0x7fffu + ((u >> 16) & 1u)) >> 16);
}
__device__ __forceinline__ unsigned int cvt_pk_bf16(float lo, float hi){
  unsigned int r;
  asm("v_cvt_pk_bf16_f32 %0, %1, %2" : "=v"(r) : "v"(lo), "v"(hi));
  return r;
}

// ---------- all 8 weight matrices f32 -> bf16 in one launch ----------
struct WPtrs { const float* w[8]; };
__global__ __launch_bounds__(256) void cvt_w_all(WPtrs wp, unsigned short* __restrict__ o){
  int t = blockIdx.x * 256 + threadIdx.x;     // 65536 threads
  int m = t >> 13, i = t & 8191;
  float2 v = ((const float2*)wp.w[m])[i];
  ((unsigned int*)o)[t] = cvt_pk_bf16(v.x, v.y);
}

// ---------- stage one 128x128 bf16 matrix into LDS, k-chunk-major ----------
__device__ __forceinline__ void stage_mat(const unsigned short* __restrict__ Bg,
                                          unsigned short* sB){
  int t = threadIdx.x; // 256
  #pragma unroll
  for (int it = 0; it < 8; ++it){
    int idx = it * 256 + t;               // kc*128 + col
    int kc = idx >> 7, col = idx & 127;
    uint4 v = *(const uint4*)(Bg + (size_t)col * DD + kc * 8);
    *(uint4*)(sB + (size_t)idx * 8) = v;
  }
}

// ---------- edge GEMM chunk: stage W once, loop `cnt` 128-row tiles ----------
__device__ __forceinline__ void edge_run(const float* __restrict__ A,
    const unsigned short* __restrict__ Wg, const float* __restrict__ bias,
    float* __restrict__ out, unsigned short* sB, int tile0, int cnt)
{
  stage_mat(Wg, sB);
  __syncthreads();
  int wave = threadIdx.x >> 6, lane = threadIdx.x & 63;
  int lr = lane & 15, lk = lane >> 4;
  float bv[8];
  #pragma unroll
  for (int j = 0; j < 8; ++j) bv[j] = bias[j * 16 + lr];

  for (int t = 0; t < cnt; ++t){
    size_t r0 = (size_t)(tile0 + t) * 128 + (size_t)wave * 32;
    const float* Ap = A + (r0 + lr) * DD + lk * 8;
    bf16x8 a[2][4];
    #pragma unroll
    for (int g = 0; g < 2; ++g){
      #pragma unroll
      for (int ks = 0; ks < 4; ++ks){
        f32x4 a0 = *(const f32x4*)(Ap + (size_t)g * 16 * DD + ks * 32);
        f32x4 a1 = *(const f32x4*)(Ap + (size_t)g * 16 * DD + ks * 32 + 4);
        union { bf16x8 v; unsigned int u[4]; } au;
        au.u[0] = cvt_pk_bf16(a0[0], a0[1]);
        au.u[1] = cvt_pk_bf16(a0[2], a0[3]);
        au.u[2] = cvt_pk_bf16(a1[0], a1[1]);
        au.u[3] = cvt_pk_bf16(a1[2], a1[3]);
        a[g][ks] = au.v;
      }
    }
    f32x4 acc[2][8];
    #pragma unroll
    for (int g = 0; g < 2; ++g)
      #pragma unroll
      for (int j = 0; j < 8; ++j) acc[g][j] = (f32x4){0.f, 0.f, 0.f, 0.f};
    #pragma unroll
    for (int ks = 0; ks < 4; ++ks){
      #pragma unroll
      for (int j = 0; j < 8; ++j){
        bf16x8 b = *(const bf16x8*)(sB + ((ks * 4 + lk) * 128 + j * 16 + lr) * 8);
        acc[0][j] = __builtin_amdgcn_mfma_f32_16x16x32_bf16(a[0][ks], b, acc[0][j], 0, 0, 0);
        acc[1][j] = __builtin_amdgcn_mfma_f32_16x16x32_bf16(a[1][ks], b, acc[1][j], 0, 0, 0);
      }
    }
    #pragma unroll
    for (int g = 0; g < 2; ++g)
      #pragma unroll
      for (int j = 0; j < 8; ++j)
        #pragma unroll
        for (int r = 0; r < 4; ++r){
          size_t row = r0 + g * 16 + lk * 4 + r;
          out[row * DD + j * 16 + lr] = fmaxf(acc[g][j][r] + bv[j], 0.f);
        }
  }
}

#define EDGE_ARGS const float* __restrict__ eA, const unsigned short* __restrict__ eW, \
                  const float* __restrict__ eBias, float* __restrict__ eOut, \
                  int eTileBase, int eBlocks
#define EDGE_PASS eA, eW, eBias, eOut
#define EDGE_CHUNK 5

// ---------- CSR count (+ edge prefix blocks) ----------
__global__ __launch_bounds__(256) void countdeg_edge(
    const int* __restrict__ dst, int* __restrict__ deg, int n, EDGE_ARGS){
  __shared__ unsigned short sB[16384];
  if ((int)blockIdx.x < eBlocks){
    edge_run(EDGE_PASS, sB, eTileBase + blockIdx.x * EDGE_CHUNK, EDGE_CHUNK);
    return;
  }
  int t = (blockIdx.x - eBlocks) * 256 + threadIdx.x;
  if (t < n) atomicAdd(&deg[dst[t]], 1);
}

// ---------- CSR fill + h0 gather (+ edge prefix blocks), 3 block ranges ----------
__global__ __launch_bounds__(256) void fillcsr_h0_edge(
    const int* __restrict__ src, const int* __restrict__ dst,
    const int* __restrict__ row_start, int* __restrict__ cursor,
    int* __restrict__ csr, int n, int csrBlk,
    const int* __restrict__ x, const float* __restrict__ item,
    unsigned short* __restrict__ h0, int nh, EDGE_ARGS){
  __shared__ unsigned short sB[16384];
  if ((int)blockIdx.x < eBlocks){
    edge_run(EDGE_PASS, sB, eTileBase + blockIdx.x * EDGE_CHUNK, EDGE_CHUNK);
    return;
  }
  int hb = blockIdx.x - eBlocks;
  if (hb < csrBlk){
    int t = hb * 256 + threadIdx.x;
    if (t < n){
      int d = dst[t];
      int pos = atomicAdd(&cursor[d], 1);
      csr[row_start[d] + pos] = src[t];
    }
    return;
  }
  int t = (hb - csrBlk) * 256 + threadIdx.x;
  if (t < nh){
    int node = t >> 6, p = t & 63;
    int s = x[node];
    float2 v = *(const float2*)(item + (size_t)s * DD + p * 2);
    ((unsigned int*)h0)[t] = cvt_pk_bf16(v.x, v.y);
  }
}

#define SCAN_CHUNK 1024
__global__ __launch_bounds__(256) void partial_sums(const int* __restrict__ deg,
                                                    int* __restrict__ partials, int n){
  __shared__ int lds[256];
  int t = threadIdx.x;
  int base = blockIdx.x * SCAN_CHUNK + t * 4;
  int s = 0;
  #pragma unroll
  for (int i = 0; i < 4; ++i){ int idx = base + i; s += (idx < n) ? deg[idx] : 0; }
  lds[t] = s; __syncthreads();
  for (int off = 128; off > 0; off >>= 1){
    if (t < off) lds[t] += lds[t + off];
    __syncthreads();
  }
  if (t == 0) partials[blockIdx.x] = lds[0];
}

// ---------- scan of partials: single-wave shfl scan (nb <= 128) ----------
__global__ __launch_bounds__(64) void scanp_wave(int* partials, int nb){
  int lane = threadIdx.x;
  int o0 = (lane < nb) ? partials[lane] : 0;
  int o1 = (lane + 64 < nb) ? partials[lane + 64] : 0;
  int v0 = o0, v1 = o1;
  #pragma unroll
  for (int off = 1; off < 64; off <<= 1){
    int t = __shfl_up(v0, off, 64);
    if (lane >= off) v0 += t;
  }
  int tot0 = __shfl(v0, 63, 64);
  #pragma unroll
  for (int off = 1; off < 64; off <<= 1){
    int t = __shfl_up(v1, off, 64);
    if (lane >= off) v1 += t;
  }
  if (lane < nb)      partials[lane]      = v0 - o0;
  if (lane + 64 < nb) partials[lane + 64] = tot0 + v1 - o1;
}

__global__ __launch_bounds__(256) void scan_block(const int* __restrict__ deg,
                                                  const int* __restrict__ partials,
                                                  int* __restrict__ row_start, int n){
  __shared__ int lds[256];
  int t = threadIdx.x;
  int base = blockIdx.x * SCAN_CHUNK + t * 4;
  int v[4]; int s = 0;
  #pragma unroll
  for (int i = 0; i < 4; ++i){ int idx = base + i; v[i] = (idx < n) ? deg[idx] : 0; s += v[i]; }
  lds[t] = s; __syncthreads();
  for (int off = 1; off < 256; off <<= 1){
    int x = (t >= off) ? lds[t - off] : 0;
    __syncthreads();
    lds[t] += x;
    __syncthreads();
  }
  int excl = ((t == 0) ? 0 : lds[t - 1]) + partials[blockIdx.x];
  #pragma unroll
  for (int i = 0; i < 4; ++i){ int idx = base + i; if (idx < n) row_start[idx] = excl; excl += v[i]; }
}

// ---------- mean aggregation: 8 neighbors in flight + scalar idx loads ----------
__global__ __launch_bounds__(256) void aggregate3(const unsigned short* __restrict__ h,
                                                  const int* __restrict__ csr,
                                                  const int* __restrict__ row_start,
                                                  const int* __restrict__ deg,
                                                  unsigned short* __restrict__ mean, int n){
  int node = blockIdx.x * 4 + (threadIdx.x >> 6);
  int lane = threadIdx.x & 63;
  // wave-uniform -> force scalar so csr index reads go down the SMEM pipe
  int st = __builtin_amdgcn_readfirstlane(row_start[node]);
  int d  = __builtin_amdgcn_readfirstlane(deg[node]);
  const unsigned int* hp = (const unsigned int*)h;
  float a0[8], a1[8];
  #pragma unroll
  for (int k = 0; k < 8; ++k){ a0[k] = 0.f; a1[k] = 0.f; }
  int i = 0;
  for (; i + 8 <= d; i += 8){
    int idx[8];
    #pragma unroll
    for (int k = 0; k < 8; ++k) idx[k] = csr[st + i + k];
    unsigned int v[8];
    #pragma unroll
    for (int k = 0; k < 8; ++k) v[k] = hp[(size_t)idx[k] * 64 + lane];
    #pragma unroll
    for (int k = 0; k < 8; ++k){
      a0[k] += bf2f((unsigned short)(v[k] & 0xffffu));
      a1[k] += bf2f((unsigned short)(v[k] >> 16));
    }
  }
  for (; i + 4 <= d; i += 4){
    int idx[4];
    #pragma unroll
    for (int k = 0; k < 4; ++k) idx[k] = csr[st + i + k];
    unsigned int v[4];
    #pragma unroll
    for (int k = 0; k < 4; ++k) v[k] = hp[(size_t)idx[k] * 64 + lane];
    #pragma unroll
    for (int k = 0; k < 4; ++k){
      a0[k] += bf2f((unsigned short)(v[k] & 0xffffu));
      a1[k] += bf2f((unsigned short)(v[k] >> 16));
    }
  }
  for (; i < d; ++i){
    int s = csr[st + i];
    unsigned int v = hp[(size_t)s * 64 + lane];
    a0[0] += bf2f((unsigned short)(v & 0xffffu));
    a1[0] += bf2f((unsigned short)(v >> 16));
  }
  float s0 = ((a0[0] + a0[1]) + (a0[2] + a0[3])) + ((a0[4] + a0[5]) + (a0[6] + a0[7]));
  float s1 = ((a1[0] + a1[1]) + (a1[2] + a1[3])) + ((a1[4] + a1[5]) + (a1[6] + a1[7]));
  float inv = 1.0f / fmaxf((float)d, 1.0f);
  ((unsigned int*)mean)[(size_t)node * 64 + lane] = cvt_pk_bf16(s0 * inv, s1 * inv);
}

// ---------- node GEMM: sequential 32KB staging (+ edge prefix blocks) ----------
template<int DUAL, int OUTF32>
__global__ __launch_bounds__(256) void node_edge(
    const unsigned short* __restrict__ A1, const unsigned short* __restrict__ B1g,
    const unsigned short* __restrict__ A2, const unsigned short* __restrict__ B2g,
    const float* __restrict__ bias, void* __restrict__ outp, int M,
    EDGE_ARGS)
{
  __shared__ unsigned short sB[16384];   // 32KB, shared by edge path and staging
  if ((int)blockIdx.x < eBlocks){
    edge_run(EDGE_PASS, sB, eTileBase + blockIdx.x * EDGE_CHUNK, EDGE_CHUNK);
    return;
  }
  stage_mat(B1g, sB);
  int wave = threadIdx.x >> 6, lane = threadIdx.x & 63;
  int lr = lane & 15, lk = lane >> 4;
  float bv[8];
  #pragma unroll
  for (int j = 0; j < 8; ++j) bv[j] = bias[j * 16 + lr];

  int tile = blockIdx.x - eBlocks;
  size_t r0 = (size_t)tile * 128 + wave * 32;
  f32x4 acc[2][8];
  #pragma unroll
  for (int g = 0; g < 2; ++g)
    #pragma unroll
    for (int j = 0; j < 8; ++j) acc[g][j] = (f32x4){0.f, 0.f, 0.f, 0.f};

  bf16x8 a[2][4];
  {
    const unsigned short* Ap = A1 + (r0 + lr) * DD + lk * 8;
    #pragma unroll
    for (int g = 0; g < 2; ++g)
      #pragma unroll
      for (int ks = 0; ks < 4; ++ks)
        a[g][ks] = *(const bf16x8*)(Ap + (size_t)g * 16 * DD + ks * 32);
  }
  __syncthreads();   // B1 staged; A1 landed
  #pragma unroll
  for (int ks = 0; ks < 4; ++ks){
    #pragma unroll
    for (int j = 0; j < 8; ++j){
      bf16x8 b = *(const bf16x8*)(sB + ((ks * 4 + lk) * 128 + j * 16 + lr) * 8);
      acc[0][j] = __builtin_amdgcn_mfma_f32_16x16x32_bf16(a[0][ks], b, acc[0][j], 0, 0, 0);
      acc[1][j] = __builtin_amdgcn_mfma_f32_16x16x32_bf16(a[1][ks], b, acc[1][j], 0, 0, 0);
    }
  }
  if (DUAL){
    __syncthreads();                 // all waves done reading B1
    stage_mat(B2g, sB);
    {
      const unsigned short* Ap = A2 + (r0 + lr) * DD + lk * 8;
      #pragma unroll
      for (int g = 0; g < 2; ++g)
        #pragma unroll
        for (int ks = 0; ks < 4; ++ks)
          a[g][ks] = *(const bf16x8*)(Ap + (size_t)g * 16 * DD + ks * 32);
    }
    __syncthreads();                 // B2 staged; A2 landed
    #pragma unroll
    for (int ks = 0; ks < 4; ++ks){
      #pragma unroll
      for (int j = 0; j < 8; ++j){
        bf16x8 b = *(const bf16x8*)(sB + ((ks * 4 + lk) * 128 + j * 16 + lr) * 8);
        acc[0][j] = __builtin_amdgcn_mfma_f32_16x16x32_bf16(a[0][ks], b, acc[0][j], 0, 0, 0);
        acc[1][j] = __builtin_amdgcn_mfma_f32_16x16x32_bf16(a[1][ks], b, acc[1][j], 0, 0, 0);
      }
    }
  }
  #pragma unroll
  for (int g = 0; g < 2; ++g)
    #pragma unroll
    for (int j = 0; j < 8; ++j)
      #pragma unroll
      for (int r = 0; r < 4; ++r){
        size_t row = r0 + g * 16 + lk * 4 + r;
        float v = fmaxf(acc[g][j][r] + bv[j], 0.f);
        if (OUTF32){
          if (row < (size_t)M) ((float*)outp)[row * DD + j * 16 + lr] = v;
        } else {
          ((unsigned short*)outp)[row * DD + j * 16 + lr] = f2bf(v);
        }
      }
}

extern "C" void kernel_launch(void* const* d_in, const int* in_sizes, int n_in,
                              void* d_out, int out_size, void* d_ws, size_t ws_size,
                              hipStream_t stream)
{
  const int*   x    = (const int*)d_in[0];
  const int*   ei   = (const int*)d_in[1];
  const int*   srcp = ei;
  const int*   dstp = ei + NE;
  const float* item = (const float*)d_in[3];
  const float* eemb = (const float*)d_in[4];
  WPtrs wp;
  wp.w[0] = (const float*)d_in[5];  // Wl1
  wp.w[1] = (const float*)d_in[7];  // Wr1
  wp.w[2] = (const float*)d_in[8];  // Wl2
  wp.w[3] = (const float*)d_in[10]; // Wr2
  wp.w[4] = (const float*)d_in[11]; // Wl3
  wp.w[5] = (const float*)d_in[13]; // Wr3
  wp.w[6] = (const float*)d_in[14]; // W_lin1
  wp.w[7] = (const float*)d_in[16]; // W_lin2
  const float* bl1 = (const float*)d_in[6];
  const float* bl2 = (const float*)d_in[9];
  const float* bl3 = (const float*)d_in[12];
  const float* bq1 = (const float*)d_in[15];
  const float* bq2 = (const float*)d_in[17];

  char* ws = (char*)d_ws;
  size_t o = 0;
  auto alloc = [&](size_t bytes) -> void* {
    void* p = ws + o;
    o += (bytes + 255) & ~(size_t)255;
    return p;
  };
  unsigned short* wbf      = (unsigned short*)alloc(8 * 16384 * 2);
  int*            deg      = (int*)alloc((size_t)NNP * 4);
  int*            cursor   = (int*)alloc((size_t)NNP * 4);
  int*            row_st   = (int*)alloc((size_t)NNP * 4);
  int*            partials = (int*)alloc(4096);
  int*            csr      = (int*)alloc((size_t)NE * 4);
  unsigned short* mean     = (unsigned short*)alloc((size_t)NNP * DD * 2);
  unsigned short* h_a      = (unsigned short*)alloc((size_t)NNP * DD * 2);
  unsigned short* h_b      = (unsigned short*)alloc((size_t)NNP * DD * 2);

  float* out_h = (float*)d_out;
  float* out_e = out_h + (size_t)NN * DD;
  const unsigned short* eW = wbf + 7 * 16384;

  // zero deg + cursor (adjacent 256-aligned allocations)
  hipMemsetAsync(deg, 0, (size_t)NNP * 4 * 2, stream);

  cvt_w_all<<<256, 256, 0, stream>>>(wp, wbf);

  // edge tile distribution: 12500 tiles total, 5 per edge block (R9 layout)
  int eb = 0;
  const int e_cd = 250, e_fc = 250, e_nd = 500, e_fin = 500;

  const int nb = (NN + SCAN_CHUNK - 1) / SCAN_CHUNK;      // 98
  const int csr_blk = (NE + 255) / 256;                   // 6250
  const int h0_blk  = (NN * 64 + 255) / 256;              // 25000

  countdeg_edge<<<e_cd + csr_blk, 256, 0, stream>>>(dstp, deg, NE,
      eemb, eW, bq2, out_e, eb * EDGE_CHUNK, e_cd); eb += e_cd;
  partial_sums<<<nb, 256, 0, stream>>>(deg, partials, NN);
  scanp_wave<<<1, 64, 0, stream>>>(partials, nb);
  scan_block<<<nb, 256, 0, stream>>>(deg, partials, row_st, NN);
  fillcsr_h0_edge<<<e_fc + csr_blk + h0_blk, 256, 0, stream>>>(
      srcp, dstp, row_st, cursor, csr, NE, csr_blk,
      x, item, h_a, NN * 64,
      eemb, eW, bq2, out_e, eb * EDGE_CHUNK, e_fc); eb += e_fc;

  const int agg_grid   = (NN + 3) / 4;      // 25000
  const int node_tiles = NNP / 128;         // 782

  // layer 1: h_a -> h_b
  aggregate3<<<agg_grid, 256, 0, stream>>>(h_a, csr, row_st, deg, mean, NN);
  node_edge<1,0><<<e_nd + node_tiles, 256, 0, stream>>>(mean, wbf + 0*16384, h_a, wbf + 1*16384,
      bl1, h_b, NN, eemb, eW, bq2, out_e, eb * EDGE_CHUNK, e_nd); eb += e_nd;
  // layer 2: h_b -> h_a
  aggregate3<<<agg_grid, 256, 0, stream>>>(h_b, csr, row_st, deg, mean, NN);
  node_edge<1,0><<<e_nd + node_tiles, 256, 0, stream>>>(mean, wbf + 2*16384, h_b, wbf + 3*16384,
      bl2, h_a, NN, eemb, eW, bq2, out_e, eb * EDGE_CHUNK, e_nd); eb += e_nd;
  // layer 3: h_a -> h_b
  aggregate3<<<agg_grid, 256, 0, stream>>>(h_a, csr, row_st, deg, mean, NN);
  node_edge<1,0><<<e_nd + node_tiles, 256, 0, stream>>>(mean, wbf + 4*16384, h_a, wbf + 5*16384,
      bl3, h_b, NN, eemb, eW, bq2, out_e, eb * EDGE_CHUNK, e_nd); eb += e_nd;

  // final node linear -> f32 out (+ last edge chunk)
  node_edge<0,1><<<e_fin + node_tiles, 256, 0, stream>>>(h_b, wbf + 6*16384, h_b, wbf + 6*16384,
      bq1, out_h, NN, eemb, eW, bq2, out_e, eb * EDGE_CHUNK, e_fin); eb += e_fin;
}

// Round 13
// 783.997 us; speedup vs baseline: 1.0778x; 1.0118x over previous
//
#include <hip/hip_runtime.h>

#define NN  100000
#define NNP 100096   // NN padded to multiple of 128
#define NE  1600000
#define DD  128

typedef __attribute__((ext_vector_type(8))) short bf16x8;
typedef __attribute__((ext_vector_type(4))) float f32x4;

__device__ __forceinline__ float bf2f(unsigned short u){
  union { unsigned int i; float f; } v; v.i = ((unsigned int)u) << 16; return v.f;
}
__device__ __forceinline__ unsigned short f2bf(float f){
  union { float f; unsigned int i; } v; v.f = f;
  unsigned int u = v.i;
  return (unsigned short)((u + 0x7fffu + ((u >> 16) & 1u)) >> 16);
}
__device__ __forceinline__ unsigned int cvt_pk_bf16(float lo, float hi){
  unsigned int r;
  asm("v_cvt_pk_bf16_f32 %0, %1, %2" : "=v"(r) : "v"(lo), "v"(hi));
  return r;
}

// ---------- all 8 weight matrices f32 -> bf16 in one launch ----------
struct WPtrs { const float* w[8]; };
__global__ __launch_bounds__(256) void cvt_w_all(WPtrs wp, unsigned short* __restrict__ o){
  int t = blockIdx.x * 256 + threadIdx.x;     // 65536 threads
  int m = t >> 13, i = t & 8191;
  float2 v = ((const float2*)wp.w[m])[i];
  ((unsigned int*)o)[t] = cvt_pk_bf16(v.x, v.y);
}

// ---------- stage one 128x128 bf16 matrix into LDS, k-chunk-major ----------
__device__ __forceinline__ void stage_mat(const unsigned short* __restrict__ Bg,
                                          unsigned short* sB){
  int t = threadIdx.x; // 256
  #pragma unroll
  for (int it = 0; it < 8; ++it){
    int idx = it * 256 + t;               // kc*128 + col
    int kc = idx >> 7, col = idx & 127;
    uint4 v = *(const uint4*)(Bg + (size_t)col * DD + kc * 8);
    *(uint4*)(sB + (size_t)idx * 8) = v;
  }
}

// ---------- edge GEMM chunk: stage W once, loop `cnt` 128-row tiles ----------
__device__ __forceinline__ void edge_run(const float* __restrict__ A,
    const unsigned short* __restrict__ Wg, const float* __restrict__ bias,
    float* __restrict__ out, unsigned short* sB, int tile0, int cnt)
{
  stage_mat(Wg, sB);
  __syncthreads();
  int wave = threadIdx.x >> 6, lane = threadIdx.x & 63;
  int lr = lane & 15, lk = lane >> 4;
  float bv[8];
  #pragma unroll
  for (int j = 0; j < 8; ++j) bv[j] = bias[j * 16 + lr];

  for (int t = 0; t < cnt; ++t){
    size_t r0 = (size_t)(tile0 + t) * 128 + (size_t)wave * 32;
    const float* Ap = A + (r0 + lr) * DD + lk * 8;
    bf16x8 a[2][4];
    #pragma unroll
    for (int g = 0; g < 2; ++g){
      #pragma unroll
      for (int ks = 0; ks < 4; ++ks){
        f32x4 a0 = *(const f32x4*)(Ap + (size_t)g * 16 * DD + ks * 32);
        f32x4 a1 = *(const f32x4*)(Ap + (size_t)g * 16 * DD + ks * 32 + 4);
        union { bf16x8 v; unsigned int u[4]; } au;
        au.u[0] = cvt_pk_bf16(a0[0], a0[1]);
        au.u[1] = cvt_pk_bf16(a0[2], a0[3]);
        au.u[2] = cvt_pk_bf16(a1[0], a1[1]);
        au.u[3] = cvt_pk_bf16(a1[2], a1[3]);
        a[g][ks] = au.v;
      }
    }
    f32x4 acc[2][8];
    #pragma unroll
    for (int g = 0; g < 2; ++g)
      #pragma unroll
      for (int j = 0; j < 8; ++j) acc[g][j] = (f32x4){0.f, 0.f, 0.f, 0.f};
    #pragma unroll
    for (int ks = 0; ks < 4; ++ks){
      #pragma unroll
      for (int j = 0; j < 8; ++j){
        bf16x8 b = *(const bf16x8*)(sB + ((ks * 4 + lk) * 128 + j * 16 + lr) * 8);
        acc[0][j] = __builtin_amdgcn_mfma_f32_16x16x32_bf16(a[0][ks], b, acc[0][j], 0, 0, 0);
        acc[1][j] = __builtin_amdgcn_mfma_f32_16x16x32_bf16(a[1][ks], b, acc[1][j], 0, 0, 0);
      }
    }
    #pragma unroll
    for (int g = 0; g < 2; ++g)
      #pragma unroll
      for (int j = 0; j < 8; ++j)
        #pragma unroll
        for (int r = 0; r < 4; ++r){
          size_t row = r0 + g * 16 + lk * 4 + r;
          out[row * DD + j * 16 + lr] = fmaxf(acc[g][j][r] + bv[j], 0.f);
        }
  }
}

#define EDGE_ARGS const float* __restrict__ eA, const unsigned short* __restrict__ eW, \
                  const float* __restrict__ eBias, float* __restrict__ eOut, \
                  int eTileBase, int eBlocks
#define EDGE_PASS eA, eW, eBias, eOut
#define EDGE_CHUNK 5

// ---------- CSR count (+ edge prefix blocks) ----------
__global__ __launch_bounds__(256) void countdeg_edge(
    const int* __restrict__ dst, int* __restrict__ deg, int n, EDGE_ARGS){
  __shared__ unsigned short sB[16384];
  if ((int)blockIdx.x < eBlocks){
    edge_run(EDGE_PASS, sB, eTileBase + blockIdx.x * EDGE_CHUNK, EDGE_CHUNK);
    return;
  }
  int t = (blockIdx.x - eBlocks) * 256 + threadIdx.x;
  if (t < n) atomicAdd(&deg[dst[t]], 1);
}

__global__ __launch_bounds__(256) void fillcsr_edge(
    const int* __restrict__ src, const int* __restrict__ dst,
    const int* __restrict__ row_start, int* __restrict__ cursor,
    int* __restrict__ csr, int n, EDGE_ARGS){
  __shared__ unsigned short sB[16384];
  if ((int)blockIdx.x < eBlocks){
    edge_run(EDGE_PASS, sB, eTileBase + blockIdx.x * EDGE_CHUNK, EDGE_CHUNK);
    return;
  }
  int t = (blockIdx.x - eBlocks) * 256 + threadIdx.x;
  if (t < n){
    int d = dst[t];
    int pos = atomicAdd(&cursor[d], 1);
    csr[row_start[d] + pos] = src[t];
  }
}

#define SCAN_CHUNK 1024
__global__ __launch_bounds__(256) void partial_sums(const int* __restrict__ deg,
                                                    int* __restrict__ partials, int n){
  __shared__ int lds[256];
  int t = threadIdx.x;
  int base = blockIdx.x * SCAN_CHUNK + t * 4;
  int s = 0;
  #pragma unroll
  for (int i = 0; i < 4; ++i){ int idx = base + i; s += (idx < n) ? deg[idx] : 0; }
  lds[t] = s; __syncthreads();
  for (int off = 128; off > 0; off >>= 1){
    if (t < off) lds[t] += lds[t + off];
    __syncthreads();
  }
  if (t == 0) partials[blockIdx.x] = lds[0];
}

// ---------- scan of partials: single-wave shfl scan (nb <= 128) ----------
__global__ __launch_bounds__(64) void scanp_wave(int* partials, int nb){
  int lane = threadIdx.x;
  int o0 = (lane < nb) ? partials[lane] : 0;
  int o1 = (lane + 64 < nb) ? partials[lane + 64] : 0;
  int v0 = o0, v1 = o1;
  #pragma unroll
  for (int off = 1; off < 64; off <<= 1){
    int t = __shfl_up(v0, off, 64);
    if (lane >= off) v0 += t;
  }
  int tot0 = __shfl(v0, 63, 64);
  #pragma unroll
  for (int off = 1; off < 64; off <<= 1){
    int t = __shfl_up(v1, off, 64);
    if (lane >= off) v1 += t;
  }
  if (lane < nb)      partials[lane]      = v0 - o0;
  if (lane + 64 < nb) partials[lane + 64] = tot0 + v1 - o1;
}

__global__ __launch_bounds__(256) void scan_block(const int* __restrict__ deg,
                                                  const int* __restrict__ partials,
                                                  int* __restrict__ row_start, int n){
  __shared__ int lds[256];
  int t = threadIdx.x;
  int base = blockIdx.x * SCAN_CHUNK + t * 4;
  int v[4]; int s = 0;
  #pragma unroll
  for (int i = 0; i < 4; ++i){ int idx = base + i; v[i] = (idx < n) ? deg[idx] : 0; s += v[i]; }
  lds[t] = s; __syncthreads();
  for (int off = 1; off < 256; off <<= 1){
    int x = (t >= off) ? lds[t - off] : 0;
    __syncthreads();
    lds[t] += x;
    __syncthreads();
  }
  int excl = ((t == 0) ? 0 : lds[t - 1]) + partials[blockIdx.x];
  #pragma unroll
  for (int i = 0; i < 4; ++i){ int idx = base + i; if (idx < n) row_start[idx] = excl; excl += v[i]; }
}

// ---------- h0 = bf16(item_emb[x]) ----------
__global__ __launch_bounds__(256) void gather_h0(const int* __restrict__ x,
                                                 const float* __restrict__ emb,
                                                 unsigned short* __restrict__ h, int n){
  int t = blockIdx.x * 256 + threadIdx.x;
  if (t >= n * 64) return;
  int node = t >> 6, p = t & 63;
  int s = x[node];
  float2 v = *(const float2*)(emb + (size_t)s * DD + p * 2);
  ((unsigned int*)h)[t] = cvt_pk_bf16(v.x, v.y);
}

// ---------- mean aggregation: 8 neighbors in flight + scalar idx loads ----------
__global__ __launch_bounds__(256) void aggregate3(const unsigned short* __restrict__ h,
                                                  const int* __restrict__ csr,
                                                  const int* __restrict__ row_start,
                                                  const int* __restrict__ deg,
                                                  unsigned short* __restrict__ mean, int n){
  int node = blockIdx.x * 4 + (threadIdx.x >> 6);
  int lane = threadIdx.x & 63;
  // wave-uniform -> force scalar so csr index reads go down the SMEM pipe
  int st = __builtin_amdgcn_readfirstlane(row_start[node]);
  int d  = __builtin_amdgcn_readfirstlane(deg[node]);
  const unsigned int* hp = (const unsigned int*)h;
  float a0[8], a1[8];
  #pragma unroll
  for (int k = 0; k < 8; ++k){ a0[k] = 0.f; a1[k] = 0.f; }
  int i = 0;
  for (; i + 8 <= d; i += 8){
    int idx[8];
    #pragma unroll
    for (int k = 0; k < 8; ++k) idx[k] = csr[st + i + k];
    unsigned int v[8];
    #pragma unroll
    for (int k = 0; k < 8; ++k) v[k] = hp[(size_t)idx[k] * 64 + lane];
    #pragma unroll
    for (int k = 0; k < 8; ++k){
      a0[k] += bf2f((unsigned short)(v[k] & 0xffffu));
      a1[k] += bf2f((unsigned short)(v[k] >> 16));
    }
  }
  for (; i + 4 <= d; i += 4){
    int idx[4];
    #pragma unroll
    for (int k = 0; k < 4; ++k) idx[k] = csr[st + i + k];
    unsigned int v[4];
    #pragma unroll
    for (int k = 0; k < 4; ++k) v[k] = hp[(size_t)idx[k] * 64 + lane];
    #pragma unroll
    for (int k = 0; k < 4; ++k){
      a0[k] += bf2f((unsigned short)(v[k] & 0xffffu));
      a1[k] += bf2f((unsigned short)(v[k] >> 16));
    }
  }
  for (; i < d; ++i){
    int s = csr[st + i];
    unsigned int v = hp[(size_t)s * 64 + lane];
    a0[0] += bf2f((unsigned short)(v & 0xffffu));
    a1[0] += bf2f((unsigned short)(v >> 16));
  }
  float s0 = ((a0[0] + a0[1]) + (a0[2] + a0[3])) + ((a0[4] + a0[5]) + (a0[6] + a0[7]));
  float s1 = ((a1[0] + a1[1]) + (a1[2] + a1[3])) + ((a1[4] + a1[5]) + (a1[6] + a1[7]));
  float inv = 1.0f / fmaxf((float)d, 1.0f);
  ((unsigned int*)mean)[(size_t)node * 64 + lane] = cvt_pk_bf16(s0 * inv, s1 * inv);
}

// ---------- node GEMM: sequential 32KB staging (+ edge prefix blocks) ----------
template<int DUAL, int OUTF32>
__global__ __launch_bounds__(256) void node_edge(
    const unsigned short* __restrict__ A1, const unsigned short* __restrict__ B1g,
    const unsigned short* __restrict__ A2, const unsigned short* __restrict__ B2g,
    const float* __restrict__ bias, void* __restrict__ outp, int M,
    EDGE_ARGS)
{
  __shared__ unsigned short sB[16384];   // 32KB, shared by edge path and staging
  if ((int)blockIdx.x < eBlocks){
    edge_run(EDGE_PASS, sB, eTileBase + blockIdx.x * EDGE_CHUNK, EDGE_CHUNK);
    return;
  }
  stage_mat(B1g, sB);
  int wave = threadIdx.x >> 6, lane = threadIdx.x & 63;
  int lr = lane & 15, lk = lane >> 4;
  float bv[8];
  #pragma unroll
  for (int j = 0; j < 8; ++j) bv[j] = bias[j * 16 + lr];

  int tile = blockIdx.x - eBlocks;
  size_t r0 = (size_t)tile * 128 + wave * 32;
  f32x4 acc[2][8];
  #pragma unroll
  for (int g = 0; g < 2; ++g)
    #pragma unroll
    for (int j = 0; j < 8; ++j) acc[g][j] = (f32x4){0.f, 0.f, 0.f, 0.f};

  bf16x8 a[2][4];
  {
    const unsigned short* Ap = A1 + (r0 + lr) * DD + lk * 8;
    #pragma unroll
    for (int g = 0; g < 2; ++g)
      #pragma unroll
      for (int ks = 0; ks < 4; ++ks)
        a[g][ks] = *(const bf16x8*)(Ap + (size_t)g * 16 * DD + ks * 32);
  }
  __syncthreads();   // B1 staged; A1 landed
  #pragma unroll
  for (int ks = 0; ks < 4; ++ks){
    #pragma unroll
    for (int j = 0; j < 8; ++j){
      bf16x8 b = *(const bf16x8*)(sB + ((ks * 4 + lk) * 128 + j * 16 + lr) * 8);
      acc[0][j] = __builtin_amdgcn_mfma_f32_16x16x32_bf16(a[0][ks], b, acc[0][j], 0, 0, 0);
      acc[1][j] = __builtin_amdgcn_mfma_f32_16x16x32_bf16(a[1][ks], b, acc[1][j], 0, 0, 0);
    }
  }
  if (DUAL){
    __syncthreads();                 // all waves done reading B1
    stage_mat(B2g, sB);
    {
      const unsigned short* Ap = A2 + (r0 + lr) * DD + lk * 8;
      #pragma unroll
      for (int g = 0; g < 2; ++g)
        #pragma unroll
        for (int ks = 0; ks < 4; ++ks)
          a[g][ks] = *(const bf16x8*)(Ap + (size_t)g * 16 * DD + ks * 32);
    }
    __syncthreads();                 // B2 staged; A2 landed
    #pragma unroll
    for (int ks = 0; ks < 4; ++ks){
      #pragma unroll
      for (int j = 0; j < 8; ++j){
        bf16x8 b = *(const bf16x8*)(sB + ((ks * 4 + lk) * 128 + j * 16 + lr) * 8);
        acc[0][j] = __builtin_amdgcn_mfma_f32_16x16x32_bf16(a[0][ks], b, acc[0][j], 0, 0, 0);
        acc[1][j] = __builtin_amdgcn_mfma_f32_16x16x32_bf16(a[1][ks], b, acc[1][j], 0, 0, 0);
      }
    }
  }
  #pragma unroll
  for (int g = 0; g < 2; ++g)
    #pragma unroll
    for (int j = 0; j < 8; ++j)
      #pragma unroll
      for (int r = 0; r < 4; ++r){
        size_t row = r0 + g * 16 + lk * 4 + r;
        float v = fmaxf(acc[g][j][r] + bv[j], 0.f);
        if (OUTF32){
          if (row < (size_t)M) ((float*)outp)[row * DD + j * 16 + lr] = v;
        } else {
          ((unsigned short*)outp)[row * DD + j * 16 + lr] = f2bf(v);
        }
      }
}

extern "C" void kernel_launch(void* const* d_in, const int* in_sizes, int n_in,
                              void* d_out, int out_size, void* d_ws, size_t ws_size,
                              hipStream_t stream)
{
  const int*   x    = (const int*)d_in[0];
  const int*   ei   = (const int*)d_in[1];
  const int*   srcp = ei;
  const int*   dstp = ei + NE;
  const float* item = (const float*)d_in[3];
  const float* eemb = (const float*)d_in[4];
  WPtrs wp;
  wp.w[0] = (const float*)d_in[5];  // Wl1
  wp.w[1] = (const float*)d_in[7];  // Wr1
  wp.w[2] = (const float*)d_in[8];  // Wl2
  wp.w[3] = (const float*)d_in[10]; // Wr2
  wp.w[4] = (const float*)d_in[11]; // Wl3
  wp.w[5] = (const float*)d_in[13]; // Wr3
  wp.w[6] = (const float*)d_in[14]; // W_lin1
  wp.w[7] = (const float*)d_in[16]; // W_lin2
  const float* bl1 = (const float*)d_in[6];
  const float* bl2 = (const float*)d_in[9];
  const float* bl3 = (const float*)d_in[12];
  const float* bq1 = (const float*)d_in[15];
  const float* bq2 = (const float*)d_in[17];

  char* ws = (char*)d_ws;
  size_t o = 0;
  auto alloc = [&](size_t bytes) -> void* {
    void* p = ws + o;
    o += (bytes + 255) & ~(size_t)255;
    return p;
  };
  unsigned short* wbf      = (unsigned short*)alloc(8 * 16384 * 2);
  int*            deg      = (int*)alloc((size_t)NNP * 4);
  int*            cursor   = (int*)alloc((size_t)NNP * 4);
  int*            row_st   = (int*)alloc((size_t)NNP * 4);
  int*            partials = (int*)alloc(4096);
  int*            csr      = (int*)alloc((size_t)NE * 4);
  unsigned short* mean     = (unsigned short*)alloc((size_t)NNP * DD * 2);
  unsigned short* h_a      = (unsigned short*)alloc((size_t)NNP * DD * 2);
  unsigned short* h_b      = (unsigned short*)alloc((size_t)NNP * DD * 2);

  float* out_h = (float*)d_out;
  float* out_e = out_h + (size_t)NN * DD;
  const unsigned short* eW = wbf + 7 * 16384;

  // zero deg + cursor (adjacent 256-aligned allocations)
  hipMemsetAsync(deg, 0, (size_t)NNP * 4 * 2, stream);

  cvt_w_all<<<256, 256, 0, stream>>>(wp, wbf);

  // edge tile distribution: 12500 tiles, 5/block, 2500 edge blocks
  // cd 250 + fc 250 + nd 550*3 + fin 350 = 2500
  int eb = 0;
  const int e_cd = 250, e_fc = 250, e_nd = 550, e_fin = 350;

  const int nb = (NN + SCAN_CHUNK - 1) / SCAN_CHUNK;      // 98
  const int csr_blk = (NE + 255) / 256;                   // 6250

  countdeg_edge<<<e_cd + csr_blk, 256, 0, stream>>>(dstp, deg, NE,
      eemb, eW, bq2, out_e, eb * EDGE_CHUNK, e_cd); eb += e_cd;
  partial_sums<<<nb, 256, 0, stream>>>(deg, partials, NN);
  scanp_wave<<<1, 64, 0, stream>>>(partials, nb);
  scan_block<<<nb, 256, 0, stream>>>(deg, partials, row_st, NN);
  fillcsr_edge<<<e_fc + csr_blk, 256, 0, stream>>>(srcp, dstp, row_st, cursor, csr, NE,
      eemb, eW, bq2, out_e, eb * EDGE_CHUNK, e_fc); eb += e_fc;

  gather_h0<<<(NN * 64 + 255) / 256, 256, 0, stream>>>(x, item, h_a, NN);

  const int agg_grid   = (NN + 3) / 4;      // 25000
  const int node_tiles = NNP / 128;         // 782

  // layer 1: h_a -> h_b
  aggregate3<<<agg_grid, 256, 0, stream>>>(h_a, csr, row_st, deg, mean, NN);
  node_edge<1,0><<<e_nd + node_tiles, 256, 0, stream>>>(mean, wbf + 0*16384, h_a, wbf + 1*16384,
      bl1, h_b, NN, eemb, eW, bq2, out_e, eb * EDGE_CHUNK, e_nd); eb += e_nd;
  // layer 2: h_b -> h_a
  aggregate3<<<agg_grid, 256, 0, stream>>>(h_b, csr, row_st, deg, mean, NN);
  node_edge<1,0><<<e_nd + node_tiles, 256, 0, stream>>>(mean, wbf + 2*16384, h_b, wbf + 3*16384,
      bl2, h_a, NN, eemb, eW, bq2, out_e, eb * EDGE_CHUNK, e_nd); eb += e_nd;
  // layer 3: h_a -> h_b
  aggregate3<<<agg_grid, 256, 0, stream>>>(h_a, csr, row_st, deg, mean, NN);
  node_edge<1,0><<<e_nd + node_tiles, 256, 0, stream>>>(mean, wbf + 4*16384, h_a, wbf + 5*16384,
      bl3, h_b, NN, eemb, eW, bq2, out_e, eb * EDGE_CHUNK, e_nd); eb += e_nd;

  // final node linear -> f32 out (+ last edge chunk)
  node_edge<0,1><<<e_fin + node_tiles, 256, 0, stream>>>(h_b, wbf + 6*16384, h_b, wbf + 6*16384,
      bq1, out_h, NN, eemb, eW, bq2, out_e, eb * EDGE_CHUNK, e_fin); eb += e_fin;
}

// Round 14
// 762.651 us; speedup vs baseline: 1.1080x; 1.0280x over previous
//
#include <hip/hip_runtime.h>

#define NN  100000
#define NNP 100096   // NN padded to multiple of 128
#define NE  1600000
#define DD  128

typedef __attribute__((ext_vector_type(8))) short bf16x8;
typedef __attribute__((ext_vector_type(4))) float f32x4;

__device__ __forceinline__ float bf2f(unsigned short u){
  union { unsigned int i; float f; } v; v.i = ((unsigned int)u) << 16; return v.f;
}
__device__ __forceinline__ unsigned short f2bf(float f){
  union { float f; unsigned int i; } v; v.f = f;
  unsigned int u = v.i;
  return (unsigned short)((u + 0x7fffu + ((u >> 16) & 1u)) >> 16);
}
__device__ __forceinline__ unsigned int cvt_pk_bf16(float lo, float hi){
  unsigned int r;
  asm("v_cvt_pk_bf16_f32 %0, %1, %2" : "=v"(r) : "v"(lo), "v"(hi));
  return r;
}

// ---------- all 8 weight matrices f32 -> bf16 in one launch ----------
struct WPtrs { const float* w[8]; };
__global__ __launch_bounds__(256) void cvt_w_all(WPtrs wp, unsigned short* __restrict__ o){
  int t = blockIdx.x * 256 + threadIdx.x;     // 65536 threads
  int m = t >> 13, i = t & 8191;
  float2 v = ((const float2*)wp.w[m])[i];
  ((unsigned int*)o)[t] = cvt_pk_bf16(v.x, v.y);
}

// ---------- stage one 128x128 bf16 matrix into LDS, k-chunk-major ----------
__device__ __forceinline__ void stage_mat(const unsigned short* __restrict__ Bg,
                                          unsigned short* sB){
  int t = threadIdx.x; // 256
  #pragma unroll
  for (int it = 0; it < 8; ++it){
    int idx = it * 256 + t;               // kc*128 + col
    int kc = idx >> 7, col = idx & 127;
    uint4 v = *(const uint4*)(Bg + (size_t)col * DD + kc * 8);
    *(uint4*)(sB + (size_t)idx * 8) = v;
  }
}

// ---------- edge GEMM chunk: stage W once, loop `cnt` 128-row tiles ----------
__device__ __forceinline__ void edge_run(const float* __restrict__ A,
    const unsigned short* __restrict__ Wg, const float* __restrict__ bias,
    float* __restrict__ out, unsigned short* sB, int tile0, int cnt)
{
  stage_mat(Wg, sB);
  __syncthreads();
  int wave = threadIdx.x >> 6, lane = threadIdx.x & 63;
  int lr = lane & 15, lk = lane >> 4;
  float bv[8];
  #pragma unroll
  for (int j = 0; j < 8; ++j) bv[j] = bias[j * 16 + lr];

  for (int t = 0; t < cnt; ++t){
    size_t r0 = (size_t)(tile0 + t) * 128 + (size_t)wave * 32;
    const float* Ap = A + (r0 + lr) * DD + lk * 8;
    bf16x8 a[2][4];
    #pragma unroll
    for (int g = 0; g < 2; ++g){
      #pragma unroll
      for (int ks = 0; ks < 4; ++ks){
        f32x4 a0 = *(const f32x4*)(Ap + (size_t)g * 16 * DD + ks * 32);
        f32x4 a1 = *(const f32x4*)(Ap + (size_t)g * 16 * DD + ks * 32 + 4);
        union { bf16x8 v; unsigned int u[4]; } au;
        au.u[0] = cvt_pk_bf16(a0[0], a0[1]);
        au.u[1] = cvt_pk_bf16(a0[2], a0[3]);
        au.u[2] = cvt_pk_bf16(a1[0], a1[1]);
        au.u[3] = cvt_pk_bf16(a1[2], a1[3]);
        a[g][ks] = au.v;
      }
    }
    f32x4 acc[2][8];
    #pragma unroll
    for (int g = 0; g < 2; ++g)
      #pragma unroll
      for (int j = 0; j < 8; ++j) acc[g][j] = (f32x4){0.f, 0.f, 0.f, 0.f};
    #pragma unroll
    for (int ks = 0; ks < 4; ++ks){
      #pragma unroll
      for (int j = 0; j < 8; ++j){
        bf16x8 b = *(const bf16x8*)(sB + ((ks * 4 + lk) * 128 + j * 16 + lr) * 8);
        acc[0][j] = __builtin_amdgcn_mfma_f32_16x16x32_bf16(a[0][ks], b, acc[0][j], 0, 0, 0);
        acc[1][j] = __builtin_amdgcn_mfma_f32_16x16x32_bf16(a[1][ks], b, acc[1][j], 0, 0, 0);
      }
    }
    #pragma unroll
    for (int g = 0; g < 2; ++g)
      #pragma unroll
      for (int j = 0; j < 8; ++j)
        #pragma unroll
        for (int r = 0; r < 4; ++r){
          size_t row = r0 + g * 16 + lk * 4 + r;
          out[row * DD + j * 16 + lr] = fmaxf(acc[g][j][r] + bv[j], 0.f);
        }
  }
}

#define EDGE_ARGS const float* __restrict__ eA, const unsigned short* __restrict__ eW, \
                  const float* __restrict__ eBias, float* __restrict__ eOut, \
                  int eTileBase, int eBlocks
#define EDGE_PASS eA, eW, eBias, eOut
#define EDGE_CHUNK 5

// ---------- CSR count (+ edge prefix blocks) ----------
__global__ __launch_bounds__(256) void countdeg_edge(
    const int* __restrict__ dst, int* __restrict__ deg, int n, EDGE_ARGS){
  __shared__ unsigned short sB[16384];
  if ((int)blockIdx.x < eBlocks){
    edge_run(EDGE_PASS, sB, eTileBase + blockIdx.x * EDGE_CHUNK, EDGE_CHUNK);
    return;
  }
  int t = (blockIdx.x - eBlocks) * 256 + threadIdx.x;
  if (t < n) atomicAdd(&deg[dst[t]], 1);
}

__global__ __launch_bounds__(256) void fillcsr_edge(
    const int* __restrict__ src, const int* __restrict__ dst,
    const int* __restrict__ row_start, int* __restrict__ cursor,
    int* __restrict__ csr, int n, EDGE_ARGS){
  __shared__ unsigned short sB[16384];
  if ((int)blockIdx.x < eBlocks){
    edge_run(EDGE_PASS, sB, eTileBase + blockIdx.x * EDGE_CHUNK, EDGE_CHUNK);
    return;
  }
  int t = (blockIdx.x - eBlocks) * 256 + threadIdx.x;
  if (t < n){
    int d = dst[t];
    int pos = atomicAdd(&cursor[d], 1);
    csr[row_start[d] + pos] = src[t];
  }
}

#define SCAN_CHUNK 1024
__global__ __launch_bounds__(256) void partial_sums(const int* __restrict__ deg,
                                                    int* __restrict__ partials, int n){
  __shared__ int lds[256];
  int t = threadIdx.x;
  int base = blockIdx.x * SCAN_CHUNK + t * 4;
  int s = 0;
  #pragma unroll
  for (int i = 0; i < 4; ++i){ int idx = base + i; s += (idx < n) ? deg[idx] : 0; }
  lds[t] = s; __syncthreads();
  for (int off = 128; off > 0; off >>= 1){
    if (t < off) lds[t] += lds[t + off];
    __syncthreads();
  }
  if (t == 0) partials[blockIdx.x] = lds[0];
}

// ---------- scan of partials: single-wave shfl scan (nb <= 128) ----------
__global__ __launch_bounds__(64) void scanp_wave(int* partials, int nb){
  int lane = threadIdx.x;
  int o0 = (lane < nb) ? partials[lane] : 0;
  int o1 = (lane + 64 < nb) ? partials[lane + 64] : 0;
  int v0 = o0, v1 = o1;
  #pragma unroll
  for (int off = 1; off < 64; off <<= 1){
    int t = __shfl_up(v0, off, 64);
    if (lane >= off) v0 += t;
  }
  int tot0 = __shfl(v0, 63, 64);
  #pragma unroll
  for (int off = 1; off < 64; off <<= 1){
    int t = __shfl_up(v1, off, 64);
    if (lane >= off) v1 += t;
  }
  if (lane < nb)      partials[lane]      = v0 - o0;
  if (lane + 64 < nb) partials[lane + 64] = tot0 + v1 - o1;
}

__global__ __launch_bounds__(256) void scan_block(const int* __restrict__ deg,
                                                  const int* __restrict__ partials,
                                                  int* __restrict__ row_start, int n){
  __shared__ int lds[256];
  int t = threadIdx.x;
  int base = blockIdx.x * SCAN_CHUNK + t * 4;
  int v[4]; int s = 0;
  #pragma unroll
  for (int i = 0; i < 4; ++i){ int idx = base + i; v[i] = (idx < n) ? deg[idx] : 0; s += v[i]; }
  lds[t] = s; __syncthreads();
  for (int off = 1; off < 256; off <<= 1){
    int x = (t >= off) ? lds[t - off] : 0;
    __syncthreads();
    lds[t] += x;
    __syncthreads();
  }
  int excl = ((t == 0) ? 0 : lds[t - 1]) + partials[blockIdx.x];
  #pragma unroll
  for (int i = 0; i < 4; ++i){ int idx = base + i; if (idx < n) row_start[idx] = excl; excl += v[i]; }
}

// ---------- h0 = bf16(item_emb[x]) ----------
__global__ __launch_bounds__(256) void gather_h0(const int* __restrict__ x,
                                                 const float* __restrict__ emb,
                                                 unsigned short* __restrict__ h, int n){
  int t = blockIdx.x * 256 + threadIdx.x;
  if (t >= n * 64) return;
  int node = t >> 6, p = t & 63;
  int s = x[node];
  float2 v = *(const float2*)(emb + (size_t)s * DD + p * 2);
  ((unsigned int*)h)[t] = cvt_pk_bf16(v.x, v.y);
}

// ---------- mean aggregation: 16 neighbors in flight + scalar idx loads ----------
__global__ __launch_bounds__(256) void aggregate16(const unsigned short* __restrict__ h,
                                                   const int* __restrict__ csr,
                                                   const int* __restrict__ row_start,
                                                   const int* __restrict__ deg,
                                                   unsigned short* __restrict__ mean, int n){
  int node = blockIdx.x * 4 + (threadIdx.x >> 6);
  int lane = threadIdx.x & 63;
  // wave-uniform -> force scalar so csr index reads go down the SMEM pipe
  int st = __builtin_amdgcn_readfirstlane(row_start[node]);
  int d  = __builtin_amdgcn_readfirstlane(deg[node]);
  const unsigned int* hp = (const unsigned int*)h;
  float a0[8], a1[8];
  #pragma unroll
  for (int k = 0; k < 8; ++k){ a0[k] = 0.f; a1[k] = 0.f; }
  int i = 0;
  for (; i + 16 <= d; i += 16){
    int idx[16];
    #pragma unroll
    for (int k = 0; k < 16; ++k) idx[k] = csr[st + i + k];
    unsigned int v[16];
    #pragma unroll
    for (int k = 0; k < 16; ++k) v[k] = hp[(size_t)idx[k] * 64 + lane];
    #pragma unroll
    for (int k = 0; k < 16; ++k){
      a0[k & 7] += bf2f((unsigned short)(v[k] & 0xffffu));
      a1[k & 7] += bf2f((unsigned short)(v[k] >> 16));
    }
  }
  for (; i + 8 <= d; i += 8){
    int idx[8];
    #pragma unroll
    for (int k = 0; k < 8; ++k) idx[k] = csr[st + i + k];
    unsigned int v[8];
    #pragma unroll
    for (int k = 0; k < 8; ++k) v[k] = hp[(size_t)idx[k] * 64 + lane];
    #pragma unroll
    for (int k = 0; k < 8; ++k){
      a0[k] += bf2f((unsigned short)(v[k] & 0xffffu));
      a1[k] += bf2f((unsigned short)(v[k] >> 16));
    }
  }
  for (; i + 4 <= d; i += 4){
    int idx[4];
    #pragma unroll
    for (int k = 0; k < 4; ++k) idx[k] = csr[st + i + k];
    unsigned int v[4];
    #pragma unroll
    for (int k = 0; k < 4; ++k) v[k] = hp[(size_t)idx[k] * 64 + lane];
    #pragma unroll
    for (int k = 0; k < 4; ++k){
      a0[k] += bf2f((unsigned short)(v[k] & 0xffffu));
      a1[k] += bf2f((unsigned short)(v[k] >> 16));
    }
  }
  for (; i < d; ++i){
    int s = csr[st + i];
    unsigned int v = hp[(size_t)s * 64 + lane];
    a0[0] += bf2f((unsigned short)(v & 0xffffu));
    a1[0] += bf2f((unsigned short)(v >> 16));
  }
  float s0 = ((a0[0] + a0[1]) + (a0[2] + a0[3])) + ((a0[4] + a0[5]) + (a0[6] + a0[7]));
  float s1 = ((a1[0] + a1[1]) + (a1[2] + a1[3])) + ((a1[4] + a1[5]) + (a1[6] + a1[7]));
  float inv = 1.0f / fmaxf((float)d, 1.0f);
  ((unsigned int*)mean)[(size_t)node * 64 + lane] = cvt_pk_bf16(s0 * inv, s1 * inv);
}

// ---------- node GEMM: sequential 32KB staging (+ edge prefix blocks) ----------
template<int DUAL, int OUTF32>
__global__ __launch_bounds__(256) void node_edge(
    const unsigned short* __restrict__ A1, const unsigned short* __restrict__ B1g,
    const unsigned short* __restrict__ A2, const unsigned short* __restrict__ B2g,
    const float* __restrict__ bias, void* __restrict__ outp, int M,
    EDGE_ARGS)
{
  __shared__ unsigned short sB[16384];   // 32KB, shared by edge path and staging
  if ((int)blockIdx.x < eBlocks){
    edge_run(EDGE_PASS, sB, eTileBase + blockIdx.x * EDGE_CHUNK, EDGE_CHUNK);
    return;
  }
  stage_mat(B1g, sB);
  int wave = threadIdx.x >> 6, lane = threadIdx.x & 63;
  int lr = lane & 15, lk = lane >> 4;
  float bv[8];
  #pragma unroll
  for (int j = 0; j < 8; ++j) bv[j] = bias[j * 16 + lr];

  int tile = blockIdx.x - eBlocks;
  size_t r0 = (size_t)tile * 128 + wave * 32;
  f32x4 acc[2][8];
  #pragma unroll
  for (int g = 0; g < 2; ++g)
    #pragma unroll
    for (int j = 0; j < 8; ++j) acc[g][j] = (f32x4){0.f, 0.f, 0.f, 0.f};

  bf16x8 a[2][4];
  {
    const unsigned short* Ap = A1 + (r0 + lr) * DD + lk * 8;
    #pragma unroll
    for (int g = 0; g < 2; ++g)
      #pragma unroll
      for (int ks = 0; ks < 4; ++ks)
        a[g][ks] = *(const bf16x8*)(Ap + (size_t)g * 16 * DD + ks * 32);
  }
  __syncthreads();   // B1 staged; A1 landed
  #pragma unroll
  for (int ks = 0; ks < 4; ++ks){
    #pragma unroll
    for (int j = 0; j < 8; ++j){
      bf16x8 b = *(const bf16x8*)(sB + ((ks * 4 + lk) * 128 + j * 16 + lr) * 8);
      acc[0][j] = __builtin_amdgcn_mfma_f32_16x16x32_bf16(a[0][ks], b, acc[0][j], 0, 0, 0);
      acc[1][j] = __builtin_amdgcn_mfma_f32_16x16x32_bf16(a[1][ks], b, acc[1][j], 0, 0, 0);
    }
  }
  if (DUAL){
    __syncthreads();                 // all waves done reading B1
    stage_mat(B2g, sB);
    {
      const unsigned short* Ap = A2 + (r0 + lr) * DD + lk * 8;
      #pragma unroll
      for (int g = 0; g < 2; ++g)
        #pragma unroll
        for (int ks = 0; ks < 4; ++ks)
          a[g][ks] = *(const bf16x8*)(Ap + (size_t)g * 16 * DD + ks * 32);
    }
    __syncthreads();                 // B2 staged; A2 landed
    #pragma unroll
    for (int ks = 0; ks < 4; ++ks){
      #pragma unroll
      for (int j = 0; j < 8; ++j){
        bf16x8 b = *(const bf16x8*)(sB + ((ks * 4 + lk) * 128 + j * 16 + lr) * 8);
        acc[0][j] = __builtin_amdgcn_mfma_f32_16x16x32_bf16(a[0][ks], b, acc[0][j], 0, 0, 0);
        acc[1][j] = __builtin_amdgcn_mfma_f32_16x16x32_bf16(a[1][ks], b, acc[1][j], 0, 0, 0);
      }
    }
  }
  #pragma unroll
  for (int g = 0; g < 2; ++g)
    #pragma unroll
    for (int j = 0; j < 8; ++j)
      #pragma unroll
      for (int r = 0; r < 4; ++r){
        size_t row = r0 + g * 16 + lk * 4 + r;
        float v = fmaxf(acc[g][j][r] + bv[j], 0.f);
        if (OUTF32){
          if (row < (size_t)M) ((float*)outp)[row * DD + j * 16 + lr] = v;
        } else {
          ((unsigned short*)outp)[row * DD + j * 16 + lr] = f2bf(v);
        }
      }
}

extern "C" void kernel_launch(void* const* d_in, const int* in_sizes, int n_in,
                              void* d_out, int out_size, void* d_ws, size_t ws_size,
                              hipStream_t stream)
{
  const int*   x    = (const int*)d_in[0];
  const int*   ei   = (const int*)d_in[1];
  const int*   srcp = ei;
  const int*   dstp = ei + NE;
  const float* item = (const float*)d_in[3];
  const float* eemb = (const float*)d_in[4];
  WPtrs wp;
  wp.w[0] = (const float*)d_in[5];  // Wl1
  wp.w[1] = (const float*)d_in[7];  // Wr1
  wp.w[2] = (const float*)d_in[8];  // Wl2
  wp.w[3] = (const float*)d_in[10]; // Wr2
  wp.w[4] = (const float*)d_in[11]; // Wl3
  wp.w[5] = (const float*)d_in[13]; // Wr3
  wp.w[6] = (const float*)d_in[14]; // W_lin1
  wp.w[7] = (const float*)d_in[16]; // W_lin2
  const float* bl1 = (const float*)d_in[6];
  const float* bl2 = (const float*)d_in[9];
  const float* bl3 = (const float*)d_in[12];
  const float* bq1 = (const float*)d_in[15];
  const float* bq2 = (const float*)d_in[17];

  char* ws = (char*)d_ws;
  size_t o = 0;
  auto alloc = [&](size_t bytes) -> void* {
    void* p = ws + o;
    o += (bytes + 255) & ~(size_t)255;
    return p;
  };
  unsigned short* wbf      = (unsigned short*)alloc(8 * 16384 * 2);
  int*            deg      = (int*)alloc((size_t)NNP * 4);
  int*            cursor   = (int*)alloc((size_t)NNP * 4);
  int*            row_st   = (int*)alloc((size_t)NNP * 4);
  int*            partials = (int*)alloc(4096);
  int*            csr      = (int*)alloc((size_t)NE * 4);
  unsigned short* mean     = (unsigned short*)alloc((size_t)NNP * DD * 2);
  unsigned short* h_a      = (unsigned short*)alloc((size_t)NNP * DD * 2);
  unsigned short* h_b      = (unsigned short*)alloc((size_t)NNP * DD * 2);

  float* out_h = (float*)d_out;
  float* out_e = out_h + (size_t)NN * DD;
  const unsigned short* eW = wbf + 7 * 16384;

  // zero deg + cursor (adjacent 256-aligned allocations)
  hipMemsetAsync(deg, 0, (size_t)NNP * 4 * 2, stream);

  cvt_w_all<<<256, 256, 0, stream>>>(wp, wbf);

  // edge tile distribution: 12500 tiles total, 5 per edge block (R9 layout)
  int eb = 0;
  const int e_cd = 250, e_fc = 250, e_nd = 500, e_fin = 500;

  const int nb = (NN + SCAN_CHUNK - 1) / SCAN_CHUNK;      // 98
  const int csr_blk = (NE + 255) / 256;                   // 6250

  countdeg_edge<<<e_cd + csr_blk, 256, 0, stream>>>(dstp, deg, NE,
      eemb, eW, bq2, out_e, eb * EDGE_CHUNK, e_cd); eb += e_cd;
  partial_sums<<<nb, 256, 0, stream>>>(deg, partials, NN);
  scanp_wave<<<1, 64, 0, stream>>>(partials, nb);
  scan_block<<<nb, 256, 0, stream>>>(deg, partials, row_st, NN);
  fillcsr_edge<<<e_fc + csr_blk, 256, 0, stream>>>(srcp, dstp, row_st, cursor, csr, NE,
      eemb, eW, bq2, out_e, eb * EDGE_CHUNK, e_fc); eb += e_fc;

  gather_h0<<<(NN * 64 + 255) / 256, 256, 0, stream>>>(x, item, h_a, NN);

  const int agg_grid   = (NN + 3) / 4;      // 25000
  const int node_tiles = NNP / 128;         // 782

  // layer 1: h_a -> h_b
  aggregate16<<<agg_grid, 256, 0, stream>>>(h_a, csr, row_st, deg, mean, NN);
  node_edge<1,0><<<e_nd + node_tiles, 256, 0, stream>>>(mean, wbf + 0*16384, h_a, wbf + 1*16384,
      bl1, h_b, NN, eemb, eW, bq2, out_e, eb * EDGE_CHUNK, e_nd); eb += e_nd;
  // layer 2: h_b -> h_a
  aggregate16<<<agg_grid, 256, 0, stream>>>(h_b, csr, row_st, deg, mean, NN);
  node_edge<1,0><<<e_nd + node_tiles, 256, 0, stream>>>(mean, wbf + 2*16384, h_b, wbf + 3*16384,
      bl2, h_a, NN, eemb, eW, bq2, out_e, eb * EDGE_CHUNK, e_nd); eb += e_nd;
  // layer 3: h_a -> h_b
  aggregate16<<<agg_grid, 256, 0, stream>>>(h_a, csr, row_st, deg, mean, NN);
  node_edge<1,0><<<e_nd + node_tiles, 256, 0, stream>>>(mean, wbf + 4*16384, h_a, wbf + 5*16384,
      bl3, h_b, NN, eemb, eW, bq2, out_e, eb * EDGE_CHUNK, e_nd); eb += e_nd;

  // final node linear -> f32 out (+ last edge chunk)
  node_edge<0,1><<<e_fin + node_tiles, 256, 0, stream>>>(h_b, wbf + 6*16384, h_b, wbf + 6*16384,
      bq1, out_h, NN, eemb, eW, bq2, out_e, eb * EDGE_CHUNK, e_fin); eb += e_fin;
}